// Round 3
// baseline (229.209 us; speedup 1.0000x reference)
//
#include <hip/hip_runtime.h>
#include <hip/hip_bf16.h>
#include <cmath>

#define BATCH 4
#define TLEN  4096
#define CEMB  1024
#define HEAD  64
#define NROWS (BATCH * TLEN)          // 16384 token rows

typedef __bf16 bf16;
typedef __attribute__((ext_vector_type(8))) __bf16 bf16x8;
typedef __attribute__((ext_vector_type(4))) __bf16 bf16x4;
typedef __attribute__((ext_vector_type(4))) float f32x4;

#define QSCALE 0.1803368801111204f    // (1/sqrt(64)) * log2(e)

static __device__ __forceinline__ f32x4 mfma16(bf16x8 a, bf16x8 b, f32x4 c) {
    return __builtin_amdgcn_mfma_f32_16x16x32_bf16(a, b, c, 0, 0, 0);
}

// ---------------------------------------------------------------------------
// Kernel 0: pack W -> Wt[n][k] bf16 (n = which*64+h, 192 rows x 1024 k).
// QSCALE folded into Wq rows.  384 KB, L2-resident for the qkv GEMM.
// Reads are strided (64B line per 4B used) but L2 catches the 16x reuse;
// writes are fully coalesced 2KB rows.
// ---------------------------------------------------------------------------
__global__ __launch_bounds__(256) void pack_w(
    const float* __restrict__ Wq, const float* __restrict__ Wk,
    const float* __restrict__ Wv, bf16* __restrict__ Wt)
{
    const int n = blockIdx.x;                 // 0..191
    const int which = n >> 6, h = n & 63;
    const float* W = which == 0 ? Wq : (which == 1 ? Wk : Wv);
    const float s = which == 0 ? QSCALE : 1.0f;
    for (int k = threadIdx.x; k < CEMB; k += 256)
        Wt[(size_t)n * CEMB + k] = (bf16)(W[(size_t)k * HEAD + h] * s);
}

// ---------------------------------------------------------------------------
// Kernel 1: QKV projection.  LDS-free, barrier-free.  n-split 2 -> 512 blocks
// (8 waves/CU).  A-frags: x rows direct from global.  B-frags: one b128 load
// from L2-hot Wt per n-tile (was 8 scalar fp32 gathers).  q pre-scaled via
// Wt; v written transposed vT[b][h][t].
// ---------------------------------------------------------------------------
__global__ __launch_bounds__(256) void qkv(
    const float* __restrict__ x, const bf16* __restrict__ Wt,
    const float* __restrict__ bq, const float* __restrict__ bk,
    const float* __restrict__ bv,
    bf16* __restrict__ qb, bf16* __restrict__ kb, bf16* __restrict__ vT)
{
    const int tid  = threadIdx.x;
    const int lane = tid & 63;
    const int wvid = tid >> 6;
    const int quad = lane >> 4;
    const int col  = lane & 15;
    const int rt   = blockIdx.x & 255;
    const int ns   = blockIdx.x >> 8;        // n-split half
    const int row0 = rt * 64 + wvid * 16;

    f32x4 acc[6] = {};
    const float* xrow = x + (size_t)(row0 + col) * CEMB + quad * 8;
    const bf16*  wbase = Wt + (size_t)(ns * 96 + col) * CEMB + quad * 8;

    #pragma unroll 4
    for (int kc = 0; kc < CEMB; kc += 32) {
        float4 a = *(const float4*)(xrow + kc);
        float4 c = *(const float4*)(xrow + kc + 4);
        bf16x8 af;
        af[0]=(bf16)a.x; af[1]=(bf16)a.y; af[2]=(bf16)a.z; af[3]=(bf16)a.w;
        af[4]=(bf16)c.x; af[5]=(bf16)c.y; af[6]=(bf16)c.z; af[7]=(bf16)c.w;
        #pragma unroll
        for (int j = 0; j < 6; ++j) {
            bf16x8 bfr = *(const bf16x8*)(wbase + (size_t)j * 16 * CEMB + kc);
            acc[j] = mfma16(af, bfr, acc[j]);
        }
    }

    const float* bias[3] = {bq, bk, bv};
    #pragma unroll
    for (int j = 0; j < 6; ++j) {
        const int jg = ns * 6 + j;            // global n-tile 0..11
        const int which = jg >> 2;
        const int h = (jg & 3) * 16 + col;
        float bb = bias[which][h];
        if (which == 0) bb *= QSCALE;
        if (which < 2) {
            bf16* dst = which == 0 ? qb : kb;
            #pragma unroll
            for (int r = 0; r < 4; ++r) {
                const int trow = row0 + quad * 4 + r;
                dst[(size_t)trow * HEAD + h] = (bf16)(acc[j][r] + bb);
            }
        } else {                              // v -> vT[b][h][t], 4 contig t
            bf16x4 pv;
            #pragma unroll
            for (int r = 0; r < 4; ++r) pv[r] = (bf16)(acc[j][r] + bb);
            const int trow0 = row0 + quad * 4;
            const int bb_   = trow0 >> 12;
            const int tt    = trow0 & (TLEN - 1);
            *(bf16x4*)(vT + ((size_t)(bb_ * HEAD + h)) * TLEN + tt) = pv;
        }
    }
}

// ---------------------------------------------------------------------------
// Kernel 2: attention, fixed-max softmax (exact: inputs bounded, exp2(L) with
// L <= ~24 cannot overflow fp32).  No running max, no alpha rescale, no
// cross-lane ops in the loop (lsum reduced once at the end).  KV-split S
// partials: split 0 -> out (fp32, unnormalized), splits >0 -> bf16 opart.
// Per-wave P bounce through LDS (in-order DS per wave, no fences needed).
// ---------------------------------------------------------------------------
template <int NQT>
__global__ __launch_bounds__(256) void attn(
    const bf16* __restrict__ qb, const bf16* __restrict__ kb,
    const bf16* __restrict__ vT,
    bf16* __restrict__ opart, float* __restrict__ lpart,
    float* __restrict__ out, int nsplit)
{
    __shared__ __align__(16) bf16 Psh[4][NQT][16][72];

    const int tid  = threadIdx.x;
    const int lane = tid & 63;
    const int wvid = tid >> 6;
    const int quad = lane >> 4;
    const int col  = lane & 15;
    const int b    = blockIdx.y;
    const int sp   = blockIdx.z;
    const int q0   = blockIdx.x * (NQT * 64) + wvid * (NQT * 16);
    const size_t rowbase = (size_t)b * TLEN + q0;

    bf16x8 qf[NQT][2];
    #pragma unroll
    for (int qt = 0; qt < NQT; ++qt) {
        const bf16* qp = qb + (rowbase + qt * 16 + col) * HEAD + quad * 8;
        qf[qt][0] = *(const bf16x8*)qp;
        qf[qt][1] = *(const bf16x8*)(qp + 32);
    }
    const bf16* kbB = kb + (size_t)b * TLEN * HEAD;
    const bf16* vTB = vT + (size_t)b * HEAD * TLEN;

    f32x4 o[NQT][4] = {};
    float lsum[NQT];
    #pragma unroll
    for (int qt = 0; qt < NQT; ++qt) lsum[qt] = 0.f;

    const int slen = TLEN / nsplit;
    const int sbeg = sp * slen;

    for (int s0 = sbeg; s0 < sbeg + slen; s0 += 64) {
        bf16x8 kf[4][2];
        #pragma unroll
        for (int t = 0; t < 4; ++t) {
            const bf16* kr = kbB + (size_t)(s0 + t * 16 + col) * HEAD + quad * 8;
            kf[t][0] = *(const bf16x8*)kr;
            kf[t][1] = *(const bf16x8*)(kr + 32);
        }
        #pragma unroll
        for (int qt = 0; qt < NQT; ++qt) {
            f32x4 st[4];
            #pragma unroll
            for (int t = 0; t < 4; ++t) {
                f32x4 z = {0.f, 0.f, 0.f, 0.f};
                z = mfma16(kf[t][0], qf[qt][0], z);
                z = mfma16(kf[t][1], qf[qt][1], z);
                st[t] = z;
            }
            // fixed-max softmax: p = exp2(logit), no reduction in the loop
            #pragma unroll
            for (int t = 0; t < 4; ++t) {
                float p0 = __builtin_amdgcn_exp2f(st[t][0]);
                float p1 = __builtin_amdgcn_exp2f(st[t][1]);
                float p2 = __builtin_amdgcn_exp2f(st[t][2]);
                float p3 = __builtin_amdgcn_exp2f(st[t][3]);
                lsum[qt] += (p0 + p1) + (p2 + p3);
                bf16x4 pv = {(bf16)p0, (bf16)p1, (bf16)p2, (bf16)p3};
                *(bf16x4*)&Psh[wvid][qt][col][t * 16 + quad * 4] = pv;
            }
        }
        bf16x8 pb[NQT][2];
        #pragma unroll
        for (int qt = 0; qt < NQT; ++qt) {
            pb[qt][0] = *(const bf16x8*)&Psh[wvid][qt][col][quad * 8];
            pb[qt][1] = *(const bf16x8*)&Psh[wvid][qt][col][32 + quad * 8];
        }
        #pragma unroll
        for (int ht = 0; ht < 4; ++ht) {
            const bf16* vr = vTB + (size_t)(ht * 16 + col) * TLEN + s0 + quad * 8;
            bf16x8 v0 = *(const bf16x8*)vr;
            bf16x8 v1 = *(const bf16x8*)(vr + 32);
            #pragma unroll
            for (int qt = 0; qt < NQT; ++qt) {
                o[qt][ht] = mfma16(v0, pb[qt][0], o[qt][ht]);
                o[qt][ht] = mfma16(v1, pb[qt][1], o[qt][ht]);
            }
        }
    }

    // one cross-lane reduction for l at the very end
    #pragma unroll
    for (int qt = 0; qt < NQT; ++qt) {
        lsum[qt] += __shfl_xor(lsum[qt], 16, 64);
        lsum[qt] += __shfl_xor(lsum[qt], 32, 64);
    }

    #pragma unroll
    for (int qt = 0; qt < NQT; ++qt) {
        const size_t grow = rowbase + qt * 16 + col;
        if (nsplit == 1) {
            const float inv = 1.f / lsum[qt];
            float* ob = out + grow * HEAD;
            #pragma unroll
            for (int ht = 0; ht < 4; ++ht) {
                f32x4 r = o[qt][ht] * inv;
                *(f32x4*)(ob + ht * 16 + quad * 4) = r;
            }
        } else if (sp == 0) {                 // split 0 partial lives in out
            float* ob = out + grow * HEAD;
            #pragma unroll
            for (int ht = 0; ht < 4; ++ht)
                *(f32x4*)(ob + ht * 16 + quad * 4) = o[qt][ht];
            if (quad == 0) lpart[grow] = lsum[qt];
        } else {                              // splits 1.. -> bf16 opart
            bf16* ob = opart + ((size_t)(sp - 1) * NROWS + grow) * HEAD;
            #pragma unroll
            for (int ht = 0; ht < 4; ++ht) {
                bf16x4 r;
                #pragma unroll
                for (int rr = 0; rr < 4; ++rr) r[rr] = (bf16)o[qt][ht][rr];
                *(bf16x4*)(ob + ht * 16 + quad * 4) = r;
            }
            if (quad == 0) lpart[(size_t)sp * NROWS + grow] = lsum[qt];
        }
    }
}

// ---------------------------------------------------------------------------
// Kernel 3: combine.  Fixed-max partials share the same scale -> plain sums.
// ---------------------------------------------------------------------------
__global__ __launch_bounds__(256) void combine(
    const bf16* __restrict__ opart, const float* __restrict__ lpart,
    float* __restrict__ out, int nsplit)
{
    const int gid = blockIdx.x * 256 + threadIdx.x;
    const int row = gid >> 4;
    const int h4  = (gid & 15) * 4;

    float L = 0.f;
    for (int s = 0; s < nsplit; ++s) L += lpart[(size_t)s * NROWS + row];
    f32x4 O = *(const f32x4*)(out + (size_t)row * HEAD + h4);
    for (int s = 1; s < nsplit; ++s) {
        bf16x4 v = *(const bf16x4*)(opart + ((size_t)(s - 1) * NROWS + row) * HEAD + h4);
        O[0] += (float)v[0]; O[1] += (float)v[1];
        O[2] += (float)v[2]; O[3] += (float)v[3];
    }
    f32x4 r = O * (1.f / L);
    *(f32x4*)(out + (size_t)row * HEAD + h4) = r;
}

// ---------------------------------------------------------------------------
extern "C" void kernel_launch(void* const* d_in, const int* in_sizes, int n_in,
                              void* d_out, int out_size, void* d_ws, size_t ws_size,
                              hipStream_t stream) {
    const float* x  = (const float*)d_in[0];
    const float* Wq = (const float*)d_in[1];
    const float* bq = (const float*)d_in[2];
    const float* Wk = (const float*)d_in[3];
    const float* bk = (const float*)d_in[4];
    const float* Wv = (const float*)d_in[5];
    const float* bv = (const float*)d_in[6];
    float* out = (float*)d_out;

    const size_t n_tok = (size_t)NROWS * HEAD;          // 1,048,576
    char* ws = (char*)d_ws;
    bf16* qb = (bf16*)ws;
    bf16* kb = qb + n_tok;
    bf16* vT = kb + n_tok;
    bf16* Wt = vT + n_tok;
    const size_t base = 3 * n_tok * sizeof(bf16) + 192 * CEMB * sizeof(bf16);

    // split-S footprint: (S-1) bf16 o-partials + S fp32 l-partials
    auto need = [&](int S) {
        return base + (size_t)(S - 1) * n_tok * sizeof(bf16)
                    + (size_t)S * NROWS * sizeof(float);
    };
    int S = 1;
    if      (ws_size >= need(8)) S = 8;
    else if (ws_size >= need(4)) S = 4;
    else if (ws_size >= need(2)) S = 2;
    bf16*  opart = Wt + 192 * CEMB;
    float* lpart = (float*)(opart + (size_t)(S - 1) * n_tok);

    pack_w<<<dim3(192), dim3(256), 0, stream>>>(Wq, Wk, Wv, Wt);
    qkv<<<dim3(512), dim3(256), 0, stream>>>(x, Wt, bq, bk, bv, qb, kb, vT);
    if (S == 1) {
        attn<1><<<dim3(TLEN / 64, BATCH, 1), dim3(256), 0, stream>>>(
            qb, kb, vT, opart, lpart, out, 1);
    } else {
        attn<2><<<dim3(TLEN / 128, BATCH, S), dim3(256), 0, stream>>>(
            qb, kb, vT, opart, lpart, out, S);
        combine<<<dim3((NROWS * 16) / 256), dim3(256), 0, stream>>>(
            opart, lpart, out, S);
    }
}

// Round 4
// 209.189 us; speedup vs baseline: 1.0957x; 1.0957x over previous
//
#include <hip/hip_runtime.h>
#include <hip/hip_bf16.h>
#include <cmath>

#define BATCH 4
#define TLEN  4096
#define CEMB  1024
#define HEAD  64
#define NROWS (BATCH * TLEN)          // 16384 token rows

typedef __bf16 bf16;
typedef __attribute__((ext_vector_type(8))) __bf16 bf16x8;
typedef __attribute__((ext_vector_type(4))) __bf16 bf16x4;
typedef __attribute__((ext_vector_type(4))) float f32x4;

#define QSCALE 0.1803368801111204f    // (1/sqrt(64)) * log2(e)

static __device__ __forceinline__ f32x4 mfma16(bf16x8 a, bf16x8 b, f32x4 c) {
    return __builtin_amdgcn_mfma_f32_16x16x32_bf16(a, b, c, 0, 0, 0);
}

// ---------------------------------------------------------------------------
// Kernel 0: pack W -> Wt[n][k] bf16 (n = which*64+h).  QSCALE folded into Wq.
// ---------------------------------------------------------------------------
__global__ __launch_bounds__(256) void pack_w(
    const float* __restrict__ Wq, const float* __restrict__ Wk,
    const float* __restrict__ Wv, bf16* __restrict__ Wt)
{
    const int n = blockIdx.x;                 // 0..191
    const int which = n >> 6, h = n & 63;
    const float* W = which == 0 ? Wq : (which == 1 ? Wk : Wv);
    const float s = which == 0 ? QSCALE : 1.0f;
    for (int k = threadIdx.x; k < CEMB; k += 256)
        Wt[(size_t)n * CEMB + k] = (bf16)(W[(size_t)k * HEAD + h] * s);
}

// ---------------------------------------------------------------------------
// Kernel 1: QKV projection.  512 blocks x 512 thr (8 waves).  Block owns 32
// token rows; wave = 16 rows (wvid&1) x 3 n-tiles (wvid>>1).  The 4 waves
// sharing a row-group hit L1 on x.  Explicit 1-chunk software prefetch of
// both x (A) and Wt (B) keeps global latency off the critical path.
// ---------------------------------------------------------------------------
__global__ __launch_bounds__(512) void qkv(
    const float* __restrict__ x, const bf16* __restrict__ Wt,
    const float* __restrict__ bq, const float* __restrict__ bk,
    const float* __restrict__ bv,
    bf16* __restrict__ qb, bf16* __restrict__ kb, bf16* __restrict__ vT)
{
    const int tid  = threadIdx.x;
    const int lane = tid & 63;
    const int wvid = tid >> 6;            // 0..7
    const int quad = lane >> 4;
    const int col  = lane & 15;
    const int rowhalf = wvid & 1;
    const int triple  = wvid >> 1;        // 0..3 -> n-tiles 3t..3t+2
    const int row0 = blockIdx.x * 32 + rowhalf * 16;

    const float* xrow = x + (size_t)(row0 + col) * CEMB + quad * 8;
    const bf16* wrow[3];
    #pragma unroll
    for (int j = 0; j < 3; ++j)
        wrow[j] = Wt + (size_t)((triple * 3 + j) * 16 + col) * CEMB + quad * 8;

    f32x4 acc[3] = {};
    float4 xa = *(const float4*)xrow;
    float4 xb = *(const float4*)(xrow + 4);
    bf16x8 wf[3];
    #pragma unroll
    for (int j = 0; j < 3; ++j) wf[j] = *(const bf16x8*)wrow[j];

    for (int kc = 0; kc < CEMB; kc += 32) {
        const int kn = (kc + 32 < CEMB) ? kc + 32 : 0;   // clamped prefetch
        float4 nxa = *(const float4*)(xrow + kn);
        float4 nxb = *(const float4*)(xrow + kn + 4);
        bf16x8 nwf[3];
        #pragma unroll
        for (int j = 0; j < 3; ++j) nwf[j] = *(const bf16x8*)(wrow[j] + kn);

        bf16x8 af;
        af[0]=(bf16)xa.x; af[1]=(bf16)xa.y; af[2]=(bf16)xa.z; af[3]=(bf16)xa.w;
        af[4]=(bf16)xb.x; af[5]=(bf16)xb.y; af[6]=(bf16)xb.z; af[7]=(bf16)xb.w;
        #pragma unroll
        for (int j = 0; j < 3; ++j) acc[j] = mfma16(af, wf[j], acc[j]);

        xa = nxa; xb = nxb;
        #pragma unroll
        for (int j = 0; j < 3; ++j) wf[j] = nwf[j];
    }

    const float* bias[3] = {bq, bk, bv};
    #pragma unroll
    for (int j = 0; j < 3; ++j) {
        const int jg = triple * 3 + j;    // global n-tile 0..11
        const int which = jg >> 2;
        const int h = (jg & 3) * 16 + col;
        float bb = bias[which][h];
        if (which == 0) bb *= QSCALE;
        if (which < 2) {
            bf16* dst = which == 0 ? qb : kb;
            #pragma unroll
            for (int r = 0; r < 4; ++r) {
                const int trow = row0 + quad * 4 + r;
                dst[(size_t)trow * HEAD + h] = (bf16)(acc[j][r] + bb);
            }
        } else {                          // v -> vT[b][h][t], 4 contig t
            bf16x4 pv;
            #pragma unroll
            for (int r = 0; r < 4; ++r) pv[r] = (bf16)(acc[j][r] + bb);
            const int trow0 = row0 + quad * 4;
            const int bb_   = trow0 >> 12;
            const int tt    = trow0 & (TLEN - 1);
            *(bf16x4*)(vT + ((size_t)(bb_ * HEAD + h)) * TLEN + tt) = pv;
        }
    }
}

// ---------------------------------------------------------------------------
// Kernel 2: attention.  Block = 4 waves, 128 q-rows; K/V chunk 64 staged in
// LDS (shared by all waves -> 4x less global traffic), double-buffered, one
// barrier/chunk; next chunk's global loads issue after the barrier and
// overlap compute.  XOR granule swizzle (slot = g ^ (row&7)) -> bank-optimal
// b128 reads.  P bounce reuses the idle Ksh back-buffer rows.  Fixed-max
// softmax (exact for bounded inputs).  Flat grid with XCD-locality decode.
// ---------------------------------------------------------------------------
__global__ __launch_bounds__(256) void attn(
    const bf16* __restrict__ qb, const bf16* __restrict__ kb,
    const bf16* __restrict__ vT,
    bf16* __restrict__ opart, float* __restrict__ lpart,
    float* __restrict__ out, int nsplit, int lg2S)
{
    __shared__ __align__(16) bf16 Ksh[2][64][64];   // 16 KB
    __shared__ __align__(16) bf16 Vsh[2][64][64];   // 16 KB (V^T: [h][s])

    const int tid  = threadIdx.x;
    const int lane = tid & 63;
    const int wvid = tid >> 6;
    const int quad = lane >> 4;
    const int col  = lane & 15;

    // block decode: give each XCD (= blockIdx%8) whole (b,sp) combos
    int b, sp, qtile;
    {
        const int id = blockIdx.x;
        if (nsplit >= 2) {
            const int cpx = (BATCH << lg2S) >> 3;   // combos per XCD
            const int idx = id >> 3;
            const int combo = (id & 7) * cpx + (idx >> 5);
            qtile = idx & 31;
            b = combo >> lg2S;
            sp = combo & (nsplit - 1);
        } else {
            qtile = id & 31; b = id >> 5; sp = 0;
        }
    }
    const int q0 = qtile * 128 + wvid * 32;
    const size_t rowbase = (size_t)b * TLEN + q0;

    bf16x8 qf[2][2];
    #pragma unroll
    for (int qt = 0; qt < 2; ++qt) {
        const bf16* qp = qb + (rowbase + qt * 16 + col) * HEAD + quad * 8;
        qf[qt][0] = *(const bf16x8*)qp;
        qf[qt][1] = *(const bf16x8*)(qp + 32);
    }
    const bf16* kbB = kb + (size_t)b * TLEN * HEAD;
    const bf16* vTB = vT + (size_t)b * HEAD * TLEN;

    f32x4 o[2][4] = {};
    float lsum[2] = {0.f, 0.f};

    const int slen = TLEN >> lg2S;
    const int sbeg = sp * slen;
    const int nch  = slen / 64;

    // staging: wave wvid stages rows wvid*16..+15 of K-tile and V-tile
    const int r_in = lane >> 3;          // 0..7
    const int seg  = lane & 7;           // global 16B granule
    const int slot = seg ^ r_in;         // swizzled LDS granule slot

    bf16x8 sK[2], sV[2];
    auto load_stage = [&](int s0) {
        #pragma unroll
        for (int j = 0; j < 2; ++j) {
            const int r = wvid * 16 + j * 8 + r_in;
            sK[j] = *(const bf16x8*)(kbB + (size_t)(s0 + r) * HEAD + seg * 8);
            sV[j] = *(const bf16x8*)(vTB + (size_t)r * TLEN + s0 + seg * 8);
        }
    };

    load_stage(sbeg);
    int buf = 0;
    for (int ci = 0; ci < nch; ++ci) {
        const int s0 = sbeg + ci * 64;
        #pragma unroll
        for (int j = 0; j < 2; ++j) {
            const int r = wvid * 16 + j * 8 + r_in;
            *(bf16x8*)&Ksh[buf][r][slot * 8] = sK[j];
            *(bf16x8*)&Vsh[buf][r][slot * 8] = sV[j];
        }
        __syncthreads();                  // stage visible; prev reads done
        const int s0n = (ci + 1 < nch) ? s0 + 64 : sbeg;
        load_stage(s0n);                  // overlaps this chunk's compute

        const int c7 = col & 7;
        bf16x8 pb[2][2];
        bf16* Pb = &Ksh[buf ^ 1][wvid * 16 + col][0];   // idle back-buffer rows
        #pragma unroll
        for (int qt = 0; qt < 2; ++qt) {
            f32x4 st[4];
            #pragma unroll
            for (int t = 0; t < 4; ++t) {
                const int r = t * 16 + col;
                bf16x8 k0 = *(const bf16x8*)&Ksh[buf][r][(quad ^ c7) * 8];
                bf16x8 k1 = *(const bf16x8*)&Ksh[buf][r][((4 + quad) ^ c7) * 8];
                f32x4 z = {0.f, 0.f, 0.f, 0.f};
                z = mfma16(k0, qf[qt][0], z);
                z = mfma16(k1, qf[qt][1], z);
                st[t] = z;
            }
            // fixed-max softmax + P bounce (per-wave rows, in-order DS)
            #pragma unroll
            for (int t = 0; t < 4; ++t) {
                float p0 = __builtin_amdgcn_exp2f(st[t][0]);
                float p1 = __builtin_amdgcn_exp2f(st[t][1]);
                float p2 = __builtin_amdgcn_exp2f(st[t][2]);
                float p3 = __builtin_amdgcn_exp2f(st[t][3]);
                lsum[qt] += (p0 + p1) + (p2 + p3);
                bf16x4 pv = {(bf16)p0, (bf16)p1, (bf16)p2, (bf16)p3};
                const int g = ((2 * t + (quad >> 1)) ^ c7) * 8 + (quad & 1) * 4;
                *(bf16x4*)(Pb + g) = pv;
            }
            pb[qt][0] = *(const bf16x8*)(Pb + ((quad ^ c7) * 8));
            pb[qt][1] = *(const bf16x8*)(Pb + (((4 + quad) ^ c7) * 8));
        }
        #pragma unroll
        for (int ht = 0; ht < 4; ++ht) {
            const int r = ht * 16 + col;
            bf16x8 v0 = *(const bf16x8*)&Vsh[buf][r][(quad ^ c7) * 8];
            bf16x8 v1 = *(const bf16x8*)&Vsh[buf][r][((4 + quad) ^ c7) * 8];
            o[0][ht] = mfma16(v0, pb[0][0], o[0][ht]);
            o[0][ht] = mfma16(v1, pb[0][1], o[0][ht]);
            o[1][ht] = mfma16(v0, pb[1][0], o[1][ht]);
            o[1][ht] = mfma16(v1, pb[1][1], o[1][ht]);
        }
        buf ^= 1;
    }

    #pragma unroll
    for (int qt = 0; qt < 2; ++qt) {
        lsum[qt] += __shfl_xor(lsum[qt], 16, 64);
        lsum[qt] += __shfl_xor(lsum[qt], 32, 64);
    }

    #pragma unroll
    for (int qt = 0; qt < 2; ++qt) {
        const size_t grow = rowbase + qt * 16 + col;
        if (nsplit == 1) {
            const float inv = 1.f / lsum[qt];
            float* ob = out + grow * HEAD;
            #pragma unroll
            for (int ht = 0; ht < 4; ++ht) {
                f32x4 r = o[qt][ht] * inv;
                *(f32x4*)(ob + ht * 16 + quad * 4) = r;
            }
        } else if (sp == 0) {             // split-0 partial lives in out (fp32)
            float* ob = out + grow * HEAD;
            #pragma unroll
            for (int ht = 0; ht < 4; ++ht)
                *(f32x4*)(ob + ht * 16 + quad * 4) = o[qt][ht];
            if (quad == 0) lpart[grow] = lsum[qt];
        } else {                          // splits 1.. -> bf16 opart
            bf16* ob = opart + ((size_t)(sp - 1) * NROWS + grow) * HEAD;
            #pragma unroll
            for (int ht = 0; ht < 4; ++ht) {
                bf16x4 r;
                #pragma unroll
                for (int rr = 0; rr < 4; ++rr) r[rr] = (bf16)o[qt][ht][rr];
                *(bf16x4*)(ob + ht * 16 + quad * 4) = r;
            }
            if (quad == 0) lpart[(size_t)sp * NROWS + grow] = lsum[qt];
        }
    }
}

// ---------------------------------------------------------------------------
// Kernel 3: combine.  Fixed-max partials share one scale -> plain sums.
// ---------------------------------------------------------------------------
__global__ __launch_bounds__(256) void combine(
    const bf16* __restrict__ opart, const float* __restrict__ lpart,
    float* __restrict__ out, int nsplit)
{
    const int gid = blockIdx.x * 256 + threadIdx.x;
    const int row = gid >> 4;
    const int h4  = (gid & 15) * 4;

    float L = 0.f;
    for (int s = 0; s < nsplit; ++s) L += lpart[(size_t)s * NROWS + row];
    f32x4 O = *(const f32x4*)(out + (size_t)row * HEAD + h4);
    for (int s = 1; s < nsplit; ++s) {
        bf16x4 v = *(const bf16x4*)(opart + ((size_t)(s - 1) * NROWS + row) * HEAD + h4);
        O[0] += (float)v[0]; O[1] += (float)v[1];
        O[2] += (float)v[2]; O[3] += (float)v[3];
    }
    f32x4 r = O * (1.f / L);
    *(f32x4*)(out + (size_t)row * HEAD + h4) = r;
}

// ---------------------------------------------------------------------------
extern "C" void kernel_launch(void* const* d_in, const int* in_sizes, int n_in,
                              void* d_out, int out_size, void* d_ws, size_t ws_size,
                              hipStream_t stream) {
    const float* x  = (const float*)d_in[0];
    const float* Wq = (const float*)d_in[1];
    const float* bq = (const float*)d_in[2];
    const float* Wk = (const float*)d_in[3];
    const float* bk = (const float*)d_in[4];
    const float* Wv = (const float*)d_in[5];
    const float* bv = (const float*)d_in[6];
    float* out = (float*)d_out;

    const size_t n_tok = (size_t)NROWS * HEAD;          // 1,048,576
    char* ws = (char*)d_ws;
    bf16* qb = (bf16*)ws;
    bf16* kb = qb + n_tok;
    bf16* vT = kb + n_tok;
    bf16* Wt = vT + n_tok;
    const size_t base = 3 * n_tok * sizeof(bf16) + 192 * CEMB * sizeof(bf16);

    auto need = [&](int S) {
        return base + (size_t)(S - 1) * n_tok * sizeof(bf16)
                    + (size_t)S * NROWS * sizeof(float);
    };
    int S = 1, lg2S = 0;
    if      (ws_size >= need(8)) { S = 8; lg2S = 3; }
    else if (ws_size >= need(4)) { S = 4; lg2S = 2; }
    else if (ws_size >= need(2)) { S = 2; lg2S = 1; }
    bf16*  opart = Wt + 192 * CEMB;
    float* lpart = (float*)(opart + (size_t)(S - 1) * n_tok);

    pack_w<<<dim3(192), dim3(256), 0, stream>>>(Wq, Wk, Wv, Wt);
    qkv<<<dim3(512), dim3(512), 0, stream>>>(x, Wt, bq, bk, bv, qb, kb, vT);
    attn<<<dim3(32 * BATCH * S), dim3(256), 0, stream>>>(
        qb, kb, vT, opart, lpart, out, S, lg2S);
    if (S > 1)
        combine<<<dim3((NROWS * 16) / 256), dim3(256), 0, stream>>>(
            opart, lpart, out, S);
}

// Round 5
// 208.147 us; speedup vs baseline: 1.1012x; 1.0050x over previous
//
#include <hip/hip_runtime.h>
#include <hip/hip_bf16.h>
#include <cmath>

#define BATCH 4
#define TLEN  4096
#define CEMB  1024
#define HEAD  64
#define NROWS (BATCH * TLEN)          // 16384 token rows

typedef __bf16 bf16;
typedef __attribute__((ext_vector_type(8))) __bf16 bf16x8;
typedef __attribute__((ext_vector_type(4))) __bf16 bf16x4;
typedef __attribute__((ext_vector_type(4))) float f32x4;

#define QSCALE 0.1803368801111204f    // (1/sqrt(64)) * log2(e)

static __device__ __forceinline__ f32x4 mfma16(bf16x8 a, bf16x8 b, f32x4 c) {
    return __builtin_amdgcn_mfma_f32_16x16x32_bf16(a, b, c, 0, 0, 0);
}

// ---------------------------------------------------------------------------
// Kernel 0: pack W -> Wt[n][k] bf16 (n = which*64+h).  QSCALE folded into Wq.
// ---------------------------------------------------------------------------
__global__ __launch_bounds__(256) void pack_w(
    const float* __restrict__ Wq, const float* __restrict__ Wk,
    const float* __restrict__ Wv, bf16* __restrict__ Wt)
{
    const int n = blockIdx.x;                 // 0..191
    const int which = n >> 6, h = n & 63;
    const float* W = which == 0 ? Wq : (which == 1 ? Wk : Wv);
    const float s = which == 0 ? QSCALE : 1.0f;
    for (int k = threadIdx.x; k < CEMB; k += 256)
        Wt[(size_t)n * CEMB + k] = (bf16)(W[(size_t)k * HEAD + h] * s);
}

// ---------------------------------------------------------------------------
// Kernel 1: QKV projection.  512 blocks x 512 thr, wave = 16 rows x 3 n-tiles.
// Memory-latency-bound fix (R4: VALUBusy 3.6%, 0.8 TB/s effective): fully
// unrolled 32-chunk k-loop with 4-deep x prefetch ring + 2-deep W ring.
// All load offsets are compile-time immediates.  ~224 B in flight per wave
// x 16 waves/CU ~= 3.6 KB/CU -> ~4-5 TB/s stream on L3-warm x.
// ---------------------------------------------------------------------------
__global__ __launch_bounds__(512, 4) void qkv(
    const float* __restrict__ x, const bf16* __restrict__ Wt,
    const float* __restrict__ bq, const float* __restrict__ bk,
    const float* __restrict__ bv,
    bf16* __restrict__ qb, bf16* __restrict__ kb, bf16* __restrict__ vT)
{
    const int tid  = threadIdx.x;
    const int lane = tid & 63;
    const int wvid = tid >> 6;            // 0..7
    const int quad = lane >> 4;
    const int col  = lane & 15;
    const int rowhalf = wvid & 1;
    const int triple  = wvid >> 1;        // 0..3 -> n-tiles 3t..3t+2
    const int row0 = blockIdx.x * 32 + rowhalf * 16;

    const float* xrow = x + (size_t)(row0 + col) * CEMB + quad * 8;
    const bf16* wrow[3];
    #pragma unroll
    for (int j = 0; j < 3; ++j)
        wrow[j] = Wt + (size_t)((triple * 3 + j) * 16 + col) * CEMB + quad * 8;

    f32x4 acc[3] = {};
    float4 xa[4], xb[4];                  // x ring, depth 4
    bf16x8 wf[2][3];                      // W ring, depth 2 (L2-hot)

    #pragma unroll
    for (int d = 0; d < 4; ++d) {
        xa[d] = *(const float4*)(xrow + d * 32);
        xb[d] = *(const float4*)(xrow + d * 32 + 4);
    }
    #pragma unroll
    for (int d = 0; d < 2; ++d)
        #pragma unroll
        for (int j = 0; j < 3; ++j)
            wf[d][j] = *(const bf16x8*)(wrow[j] + d * 32);

    #pragma unroll
    for (int c = 0; c < 32; ++c) {        // chunk = 32 k
        float4 a = xa[c & 3], b = xb[c & 3];
        bf16x8 w0 = wf[c & 1][0], w1 = wf[c & 1][1], w2 = wf[c & 1][2];
        if (c + 4 < 32) {                 // compile-time after unroll
            xa[c & 3] = *(const float4*)(xrow + (c + 4) * 32);
            xb[c & 3] = *(const float4*)(xrow + (c + 4) * 32 + 4);
        }
        if (c + 2 < 32) {
            #pragma unroll
            for (int j = 0; j < 3; ++j)
                wf[c & 1][j] = *(const bf16x8*)(wrow[j] + (c + 2) * 32);
        }
        bf16x8 af;
        af[0]=(bf16)a.x; af[1]=(bf16)a.y; af[2]=(bf16)a.z; af[3]=(bf16)a.w;
        af[4]=(bf16)b.x; af[5]=(bf16)b.y; af[6]=(bf16)b.z; af[7]=(bf16)b.w;
        acc[0] = mfma16(af, w0, acc[0]);
        acc[1] = mfma16(af, w1, acc[1]);
        acc[2] = mfma16(af, w2, acc[2]);
    }

    const float* bias[3] = {bq, bk, bv};
    #pragma unroll
    for (int j = 0; j < 3; ++j) {
        const int jg = triple * 3 + j;    // global n-tile 0..11
        const int which = jg >> 2;
        const int h = (jg & 3) * 16 + col;
        float bb = bias[which][h];
        if (which == 0) bb *= QSCALE;
        if (which < 2) {
            bf16* dst = which == 0 ? qb : kb;
            #pragma unroll
            for (int r = 0; r < 4; ++r) {
                const int trow = row0 + quad * 4 + r;
                dst[(size_t)trow * HEAD + h] = (bf16)(acc[j][r] + bb);
            }
        } else {                          // v -> vT[b][h][t], 4 contig t
            bf16x4 pv;
            #pragma unroll
            for (int r = 0; r < 4; ++r) pv[r] = (bf16)(acc[j][r] + bb);
            const int trow0 = row0 + quad * 4;
            const int bb_   = trow0 >> 12;
            const int tt    = trow0 & (TLEN - 1);
            *(bf16x4*)(vT + ((size_t)(bb_ * HEAD + h)) * TLEN + tt) = pv;
        }
    }
}

// ---------------------------------------------------------------------------
// Kernel 2: attention.  Block = 4 waves, 128 q-rows; K/V chunk 64 staged in
// LDS (shared by all waves), double-buffered, one barrier/chunk; next chunk's
// global loads issue after the barrier and overlap compute.  XOR granule
// swizzle -> bank-optimal b128 reads.  P bounce reuses idle back-buffer rows.
// Fixed-max softmax (exact for bounded inputs).  XCD-locality block decode.
// ---------------------------------------------------------------------------
__global__ __launch_bounds__(256) void attn(
    const bf16* __restrict__ qb, const bf16* __restrict__ kb,
    const bf16* __restrict__ vT,
    bf16* __restrict__ opart, float* __restrict__ lpart,
    float* __restrict__ out, int nsplit, int lg2S)
{
    __shared__ __align__(16) bf16 Ksh[2][64][64];   // 16 KB
    __shared__ __align__(16) bf16 Vsh[2][64][64];   // 16 KB (V^T: [h][s])

    const int tid  = threadIdx.x;
    const int lane = tid & 63;
    const int wvid = tid >> 6;
    const int quad = lane >> 4;
    const int col  = lane & 15;

    int b, sp, qtile;
    {
        const int id = blockIdx.x;
        if (nsplit >= 2) {
            const int cpx = (BATCH << lg2S) >> 3;   // combos per XCD
            const int idx = id >> 3;
            const int combo = (id & 7) * cpx + (idx >> 5);
            qtile = idx & 31;
            b = combo >> lg2S;
            sp = combo & (nsplit - 1);
        } else {
            qtile = id & 31; b = id >> 5; sp = 0;
        }
    }
    const int q0 = qtile * 128 + wvid * 32;
    const size_t rowbase = (size_t)b * TLEN + q0;

    bf16x8 qf[2][2];
    #pragma unroll
    for (int qt = 0; qt < 2; ++qt) {
        const bf16* qp = qb + (rowbase + qt * 16 + col) * HEAD + quad * 8;
        qf[qt][0] = *(const bf16x8*)qp;
        qf[qt][1] = *(const bf16x8*)(qp + 32);
    }
    const bf16* kbB = kb + (size_t)b * TLEN * HEAD;
    const bf16* vTB = vT + (size_t)b * HEAD * TLEN;

    f32x4 o[2][4] = {};
    float lsum[2] = {0.f, 0.f};

    const int slen = TLEN >> lg2S;
    const int sbeg = sp * slen;
    const int nch  = slen / 64;

    const int r_in = lane >> 3;          // 0..7
    const int seg  = lane & 7;           // global 16B granule
    const int slot = seg ^ r_in;         // swizzled LDS granule slot

    bf16x8 sK[2], sV[2];
    auto load_stage = [&](int s0) {
        #pragma unroll
        for (int j = 0; j < 2; ++j) {
            const int r = wvid * 16 + j * 8 + r_in;
            sK[j] = *(const bf16x8*)(kbB + (size_t)(s0 + r) * HEAD + seg * 8);
            sV[j] = *(const bf16x8*)(vTB + (size_t)r * TLEN + s0 + seg * 8);
        }
    };

    load_stage(sbeg);
    int buf = 0;
    for (int ci = 0; ci < nch; ++ci) {
        const int s0 = sbeg + ci * 64;
        #pragma unroll
        for (int j = 0; j < 2; ++j) {
            const int r = wvid * 16 + j * 8 + r_in;
            *(bf16x8*)&Ksh[buf][r][slot * 8] = sK[j];
            *(bf16x8*)&Vsh[buf][r][slot * 8] = sV[j];
        }
        __syncthreads();
        const int s0n = (ci + 1 < nch) ? s0 + 64 : sbeg;
        load_stage(s0n);                  // overlaps this chunk's compute

        const int c7 = col & 7;
        bf16x8 pb[2][2];
        bf16* Pb = &Ksh[buf ^ 1][wvid * 16 + col][0];   // idle back-buffer rows
        #pragma unroll
        for (int qt = 0; qt < 2; ++qt) {
            f32x4 st[4];
            #pragma unroll
            for (int t = 0; t < 4; ++t) {
                const int r = t * 16 + col;
                bf16x8 k0 = *(const bf16x8*)&Ksh[buf][r][(quad ^ c7) * 8];
                bf16x8 k1 = *(const bf16x8*)&Ksh[buf][r][((4 + quad) ^ c7) * 8];
                f32x4 z = {0.f, 0.f, 0.f, 0.f};
                z = mfma16(k0, qf[qt][0], z);
                z = mfma16(k1, qf[qt][1], z);
                st[t] = z;
            }
            #pragma unroll
            for (int t = 0; t < 4; ++t) {
                float p0 = __builtin_amdgcn_exp2f(st[t][0]);
                float p1 = __builtin_amdgcn_exp2f(st[t][1]);
                float p2 = __builtin_amdgcn_exp2f(st[t][2]);
                float p3 = __builtin_amdgcn_exp2f(st[t][3]);
                lsum[qt] += (p0 + p1) + (p2 + p3);
                bf16x4 pv = {(bf16)p0, (bf16)p1, (bf16)p2, (bf16)p3};
                const int g = ((2 * t + (quad >> 1)) ^ c7) * 8 + (quad & 1) * 4;
                *(bf16x4*)(Pb + g) = pv;
            }
            pb[qt][0] = *(const bf16x8*)(Pb + ((quad ^ c7) * 8));
            pb[qt][1] = *(const bf16x8*)(Pb + (((4 + quad) ^ c7) * 8));
        }
        #pragma unroll
        for (int ht = 0; ht < 4; ++ht) {
            const int r = ht * 16 + col;
            bf16x8 v0 = *(const bf16x8*)&Vsh[buf][r][(quad ^ c7) * 8];
            bf16x8 v1 = *(const bf16x8*)&Vsh[buf][r][((4 + quad) ^ c7) * 8];
            o[0][ht] = mfma16(v0, pb[0][0], o[0][ht]);
            o[0][ht] = mfma16(v1, pb[0][1], o[0][ht]);
            o[1][ht] = mfma16(v0, pb[1][0], o[1][ht]);
            o[1][ht] = mfma16(v1, pb[1][1], o[1][ht]);
        }
        buf ^= 1;
    }

    #pragma unroll
    for (int qt = 0; qt < 2; ++qt) {
        lsum[qt] += __shfl_xor(lsum[qt], 16, 64);
        lsum[qt] += __shfl_xor(lsum[qt], 32, 64);
    }

    #pragma unroll
    for (int qt = 0; qt < 2; ++qt) {
        const size_t grow = rowbase + qt * 16 + col;
        if (nsplit == 1) {
            const float inv = 1.f / lsum[qt];
            float* ob = out + grow * HEAD;
            #pragma unroll
            for (int ht = 0; ht < 4; ++ht) {
                f32x4 r = o[qt][ht] * inv;
                *(f32x4*)(ob + ht * 16 + quad * 4) = r;
            }
        } else if (sp == 0) {             // split-0 partial lives in out (fp32)
            float* ob = out + grow * HEAD;
            #pragma unroll
            for (int ht = 0; ht < 4; ++ht)
                *(f32x4*)(ob + ht * 16 + quad * 4) = o[qt][ht];
            if (quad == 0) lpart[grow] = lsum[qt];
        } else {                          // splits 1.. -> bf16 opart
            bf16* ob = opart + ((size_t)(sp - 1) * NROWS + grow) * HEAD;
            #pragma unroll
            for (int ht = 0; ht < 4; ++ht) {
                bf16x4 r;
                #pragma unroll
                for (int rr = 0; rr < 4; ++rr) r[rr] = (bf16)o[qt][ht][rr];
                *(bf16x4*)(ob + ht * 16 + quad * 4) = r;
            }
            if (quad == 0) lpart[(size_t)sp * NROWS + grow] = lsum[qt];
        }
    }
}

// ---------------------------------------------------------------------------
// Kernel 3: combine.  Fixed-max partials share one scale -> plain sums.
// ---------------------------------------------------------------------------
__global__ __launch_bounds__(256) void combine(
    const bf16* __restrict__ opart, const float* __restrict__ lpart,
    float* __restrict__ out, int nsplit)
{
    const int gid = blockIdx.x * 256 + threadIdx.x;
    const int row = gid >> 4;
    const int h4  = (gid & 15) * 4;

    float L = 0.f;
    for (int s = 0; s < nsplit; ++s) L += lpart[(size_t)s * NROWS + row];
    f32x4 O = *(const f32x4*)(out + (size_t)row * HEAD + h4);
    for (int s = 1; s < nsplit; ++s) {
        bf16x4 v = *(const bf16x4*)(opart + ((size_t)(s - 1) * NROWS + row) * HEAD + h4);
        O[0] += (float)v[0]; O[1] += (float)v[1];
        O[2] += (float)v[2]; O[3] += (float)v[3];
    }
    f32x4 r = O * (1.f / L);
    *(f32x4*)(out + (size_t)row * HEAD + h4) = r;
}

// ---------------------------------------------------------------------------
extern "C" void kernel_launch(void* const* d_in, const int* in_sizes, int n_in,
                              void* d_out, int out_size, void* d_ws, size_t ws_size,
                              hipStream_t stream) {
    const float* x  = (const float*)d_in[0];
    const float* Wq = (const float*)d_in[1];
    const float* bq = (const float*)d_in[2];
    const float* Wk = (const float*)d_in[3];
    const float* bk = (const float*)d_in[4];
    const float* Wv = (const float*)d_in[5];
    const float* bv = (const float*)d_in[6];
    float* out = (float*)d_out;

    const size_t n_tok = (size_t)NROWS * HEAD;          // 1,048,576
    char* ws = (char*)d_ws;
    bf16* qb = (bf16*)ws;
    bf16* kb = qb + n_tok;
    bf16* vT = kb + n_tok;
    bf16* Wt = vT + n_tok;
    const size_t base = 3 * n_tok * sizeof(bf16) + 192 * CEMB * sizeof(bf16);

    auto need = [&](int S) {
        return base + (size_t)(S - 1) * n_tok * sizeof(bf16)
                    + (size_t)S * NROWS * sizeof(float);
    };
    int S = 1, lg2S = 0;
    if      (ws_size >= need(8)) { S = 8; lg2S = 3; }
    else if (ws_size >= need(4)) { S = 4; lg2S = 2; }
    else if (ws_size >= need(2)) { S = 2; lg2S = 1; }
    bf16*  opart = Wt + 192 * CEMB;
    float* lpart = (float*)(opart + (size_t)(S - 1) * n_tok);

    pack_w<<<dim3(192), dim3(256), 0, stream>>>(Wq, Wk, Wv, Wt);
    qkv<<<dim3(512), dim3(512), 0, stream>>>(x, Wt, bq, bk, bv, qb, kb, vT);
    attn<<<dim3(32 * BATCH * S), dim3(256), 0, stream>>>(
        qb, kb, vT, opart, lpart, out, S, lg2S);
    if (S > 1)
        combine<<<dim3((NROWS * 16) / 256), dim3(256), 0, stream>>>(
            opart, lpart, out, S);
}

// Round 6
// 187.484 us; speedup vs baseline: 1.2226x; 1.1102x over previous
//
#include <hip/hip_runtime.h>
#include <hip/hip_bf16.h>
#include <cmath>

#define BATCH 4
#define TLEN  4096
#define CEMB  1024
#define HEAD  64
#define NROWS (BATCH * TLEN)          // 16384 token rows

typedef __bf16 bf16;
typedef __attribute__((ext_vector_type(8))) __bf16 bf16x8;
typedef __attribute__((ext_vector_type(4))) __bf16 bf16x4;
typedef __attribute__((ext_vector_type(4))) float f32x4;

#define QSCALE 0.1803368801111204f    // (1/sqrt(64)) * log2(e)

static __device__ __forceinline__ f32x4 mfma16(bf16x8 a, bf16x8 b, f32x4 c) {
    return __builtin_amdgcn_mfma_f32_16x16x32_bf16(a, b, c, 0, 0, 0);
}

// ---------------------------------------------------------------------------
// Kernel 0: pack W -> Wt[n][k] bf16 (n = which*64+h).  QSCALE folded into Wq.
// ---------------------------------------------------------------------------
__global__ __launch_bounds__(256) void pack_w(
    const float* __restrict__ Wq, const float* __restrict__ Wk,
    const float* __restrict__ Wv, bf16* __restrict__ Wt)
{
    const int n = blockIdx.x;                 // 0..191
    const int which = n >> 6, h = n & 63;
    const float* W = which == 0 ? Wq : (which == 1 ? Wk : Wv);
    const float s = which == 0 ? QSCALE : 1.0f;
    for (int k = threadIdx.x; k < CEMB; k += 256)
        Wt[(size_t)n * CEMB + k] = (bf16)(W[(size_t)k * HEAD + h] * s);
}

// ---------------------------------------------------------------------------
// Kernel 1: QKV projection, v3.  R5 post-mortem: VGPR ring prefetch was
// compiled away (VGPR_Count=32 -> loads sunk to uses -> latency-bound at
// 0.8 TB/s).  Fix: LDS-staged double-buffered K-loop (the only structure
// with measured in-flight persistence): x chunk (32 rows x 64 k fp32)
// staged to swizzled LDS per chunk, one barrier/chunk, next chunk's global
// loads issued right after the barrier so they stay outstanding across the
// chunk's compute.  Wave = 16 rows x 6 n-tiles; Wt B-frags from L2-hot
// global with a depth-2 register ring.  Grid 512 -> 2 blocks/CU.
// ---------------------------------------------------------------------------
__global__ __launch_bounds__(256, 2) void qkv(
    const float* __restrict__ x, const bf16* __restrict__ Wt,
    const float* __restrict__ bq, const float* __restrict__ bk,
    const float* __restrict__ bv,
    bf16* __restrict__ qb, bf16* __restrict__ kb, bf16* __restrict__ vT)
{
    __shared__ __align__(16) bf16 Xsh[2][32][64];   // 8 KB, XOR-swizzled

    const int tid  = threadIdx.x;
    const int lane = tid & 63;
    const int wvid = tid >> 6;            // 0..3
    const int quad = lane >> 4;
    const int col  = lane & 15;
    const int rowhalf = wvid >> 1;        // rows rowhalf*16 ..
    const int nhalf   = wvid & 1;         // n-tiles nhalf*6 ..
    const int row0 = blockIdx.x * 32;     // grid 512

    // staging map: thread t -> row t>>3, 16B granule t&7, XOR slot
    const int srow  = tid >> 3;           // 0..31
    const int sseg  = tid & 7;
    const int sslot = sseg ^ (srow & 7);
    const float* xsrc = x + (size_t)(row0 + srow) * CEMB + sseg * 8;

    const bf16* wrow[6];
    #pragma unroll
    for (int j = 0; j < 6; ++j)
        wrow[j] = Wt + (size_t)((nhalf * 6 + j) * 16 + col) * CEMB + quad * 8;

    f32x4 acc[6] = {};

    // prefetch chunk 0 stage + B ring h=0
    float4 xa = *(const float4*)xsrc;
    float4 xb = *(const float4*)(xsrc + 4);
    bf16x8 Bf[2][6];
    #pragma unroll
    for (int j = 0; j < 6; ++j) Bf[0][j] = *(const bf16x8*)wrow[j];

    const int arow = rowhalf * 16 + col;
    const int c7   = col & 7;

    int buf = 0;
    for (int ci = 0; ci < 16; ++ci) {
        // park staged x in LDS (frees regs), one barrier per chunk
        bf16x8 xv;
        xv[0]=(bf16)xa.x; xv[1]=(bf16)xa.y; xv[2]=(bf16)xa.z; xv[3]=(bf16)xa.w;
        xv[4]=(bf16)xb.x; xv[5]=(bf16)xb.y; xv[6]=(bf16)xb.z; xv[7]=(bf16)xb.w;
        *(bf16x8*)&Xsh[buf][srow][sslot * 8] = xv;
        __syncthreads();

        // issue next chunk's x loads NOW -> outstanding across this compute
        if (ci + 1 < 16) {
            xa = *(const float4*)(xsrc + (ci + 1) * 64);
            xb = *(const float4*)(xsrc + (ci + 1) * 64 + 4);
        }

        #pragma unroll
        for (int kk = 0; kk < 2; ++kk) {
            const int h = ci * 2 + kk;
            if (h + 1 < 32) {             // B ring prefetch, depth 2 (L2-hot)
                #pragma unroll
                for (int j = 0; j < 6; ++j)
                    Bf[(h + 1) & 1][j] = *(const bf16x8*)(wrow[j] + (h + 1) * 32);
            }
            bf16x8 af = *(const bf16x8*)
                &Xsh[buf][arow][((kk * 4 + quad) ^ c7) * 8];
            #pragma unroll
            for (int j = 0; j < 6; ++j)
                acc[j] = mfma16(af, Bf[h & 1][j], acc[j]);
        }
        buf ^= 1;
    }

    const float* bias[3] = {bq, bk, bv};
    #pragma unroll
    for (int j = 0; j < 6; ++j) {
        const int jg = nhalf * 6 + j;     // global n-tile 0..11
        const int which = jg >> 2;
        const int h = (jg & 3) * 16 + col;
        float bb = bias[which][h];
        if (which == 0) bb *= QSCALE;
        if (which < 2) {
            bf16* dst = which == 0 ? qb : kb;
            #pragma unroll
            for (int r = 0; r < 4; ++r) {
                const int trow = row0 + rowhalf * 16 + quad * 4 + r;
                dst[(size_t)trow * HEAD + h] = (bf16)(acc[j][r] + bb);
            }
        } else {                          // v -> vT[b][h][t], 4 contig t
            bf16x4 pv;
            #pragma unroll
            for (int r = 0; r < 4; ++r) pv[r] = (bf16)(acc[j][r] + bb);
            const int trow0 = row0 + rowhalf * 16 + quad * 4;
            const int bb_   = trow0 >> 12;
            const int tt    = trow0 & (TLEN - 1);
            *(bf16x4*)(vT + ((size_t)(bb_ * HEAD + h)) * TLEN + tt) = pv;
        }
    }
}

// ---------------------------------------------------------------------------
// Kernel 2: attention (unchanged from R4/R5).  Block = 4 waves, 128 q-rows;
// K/V chunk 64 staged in LDS, double-buffered, one barrier/chunk; XOR
// granule swizzle; P bounce in idle back-buffer rows; fixed-max softmax;
// XCD-locality block decode.
// ---------------------------------------------------------------------------
__global__ __launch_bounds__(256) void attn(
    const bf16* __restrict__ qb, const bf16* __restrict__ kb,
    const bf16* __restrict__ vT,
    bf16* __restrict__ opart, float* __restrict__ lpart,
    float* __restrict__ out, int nsplit, int lg2S)
{
    __shared__ __align__(16) bf16 Ksh[2][64][64];   // 16 KB
    __shared__ __align__(16) bf16 Vsh[2][64][64];   // 16 KB (V^T: [h][s])

    const int tid  = threadIdx.x;
    const int lane = tid & 63;
    const int wvid = tid >> 6;
    const int quad = lane >> 4;
    const int col  = lane & 15;

    int b, sp, qtile;
    {
        const int id = blockIdx.x;
        if (nsplit >= 2) {
            const int cpx = (BATCH << lg2S) >> 3;   // combos per XCD
            const int idx = id >> 3;
            const int combo = (id & 7) * cpx + (idx >> 5);
            qtile = idx & 31;
            b = combo >> lg2S;
            sp = combo & (nsplit - 1);
        } else {
            qtile = id & 31; b = id >> 5; sp = 0;
        }
    }
    const int q0 = qtile * 128 + wvid * 32;
    const size_t rowbase = (size_t)b * TLEN + q0;

    bf16x8 qf[2][2];
    #pragma unroll
    for (int qt = 0; qt < 2; ++qt) {
        const bf16* qp = qb + (rowbase + qt * 16 + col) * HEAD + quad * 8;
        qf[qt][0] = *(const bf16x8*)qp;
        qf[qt][1] = *(const bf16x8*)(qp + 32);
    }
    const bf16* kbB = kb + (size_t)b * TLEN * HEAD;
    const bf16* vTB = vT + (size_t)b * HEAD * TLEN;

    f32x4 o[2][4] = {};
    float lsum[2] = {0.f, 0.f};

    const int slen = TLEN >> lg2S;
    const int sbeg = sp * slen;
    const int nch  = slen / 64;

    const int r_in = lane >> 3;          // 0..7
    const int seg  = lane & 7;           // global 16B granule
    const int slot = seg ^ r_in;         // swizzled LDS granule slot

    bf16x8 sK[2], sV[2];
    auto load_stage = [&](int s0) {
        #pragma unroll
        for (int j = 0; j < 2; ++j) {
            const int r = wvid * 16 + j * 8 + r_in;
            sK[j] = *(const bf16x8*)(kbB + (size_t)(s0 + r) * HEAD + seg * 8);
            sV[j] = *(const bf16x8*)(vTB + (size_t)r * TLEN + s0 + seg * 8);
        }
    };

    load_stage(sbeg);
    int buf = 0;
    for (int ci = 0; ci < nch; ++ci) {
        const int s0 = sbeg + ci * 64;
        #pragma unroll
        for (int j = 0; j < 2; ++j) {
            const int r = wvid * 16 + j * 8 + r_in;
            *(bf16x8*)&Ksh[buf][r][slot * 8] = sK[j];
            *(bf16x8*)&Vsh[buf][r][slot * 8] = sV[j];
        }
        __syncthreads();
        const int s0n = (ci + 1 < nch) ? s0 + 64 : sbeg;
        load_stage(s0n);                  // overlaps this chunk's compute

        const int c7 = col & 7;
        bf16x8 pb[2][2];
        bf16* Pb = &Ksh[buf ^ 1][wvid * 16 + col][0];   // idle back-buffer rows
        #pragma unroll
        for (int qt = 0; qt < 2; ++qt) {
            f32x4 st[4];
            #pragma unroll
            for (int t = 0; t < 4; ++t) {
                const int r = t * 16 + col;
                bf16x8 k0 = *(const bf16x8*)&Ksh[buf][r][(quad ^ c7) * 8];
                bf16x8 k1 = *(const bf16x8*)&Ksh[buf][r][((4 + quad) ^ c7) * 8];
                f32x4 z = {0.f, 0.f, 0.f, 0.f};
                z = mfma16(k0, qf[qt][0], z);
                z = mfma16(k1, qf[qt][1], z);
                st[t] = z;
            }
            #pragma unroll
            for (int t = 0; t < 4; ++t) {
                float p0 = __builtin_amdgcn_exp2f(st[t][0]);
                float p1 = __builtin_amdgcn_exp2f(st[t][1]);
                float p2 = __builtin_amdgcn_exp2f(st[t][2]);
                float p3 = __builtin_amdgcn_exp2f(st[t][3]);
                lsum[qt] += (p0 + p1) + (p2 + p3);
                bf16x4 pv = {(bf16)p0, (bf16)p1, (bf16)p2, (bf16)p3};
                const int g = ((2 * t + (quad >> 1)) ^ c7) * 8 + (quad & 1) * 4;
                *(bf16x4*)(Pb + g) = pv;
            }
            pb[qt][0] = *(const bf16x8*)(Pb + ((quad ^ c7) * 8));
            pb[qt][1] = *(const bf16x8*)(Pb + (((4 + quad) ^ c7) * 8));
        }
        #pragma unroll
        for (int ht = 0; ht < 4; ++ht) {
            const int r = ht * 16 + col;
            bf16x8 v0 = *(const bf16x8*)&Vsh[buf][r][(quad ^ c7) * 8];
            bf16x8 v1 = *(const bf16x8*)&Vsh[buf][r][((4 + quad) ^ c7) * 8];
            o[0][ht] = mfma16(v0, pb[0][0], o[0][ht]);
            o[0][ht] = mfma16(v1, pb[0][1], o[0][ht]);
            o[1][ht] = mfma16(v0, pb[1][0], o[1][ht]);
            o[1][ht] = mfma16(v1, pb[1][1], o[1][ht]);
        }
        buf ^= 1;
    }

    #pragma unroll
    for (int qt = 0; qt < 2; ++qt) {
        lsum[qt] += __shfl_xor(lsum[qt], 16, 64);
        lsum[qt] += __shfl_xor(lsum[qt], 32, 64);
    }

    #pragma unroll
    for (int qt = 0; qt < 2; ++qt) {
        const size_t grow = rowbase + qt * 16 + col;
        if (nsplit == 1) {
            const float inv = 1.f / lsum[qt];
            float* ob = out + grow * HEAD;
            #pragma unroll
            for (int ht = 0; ht < 4; ++ht) {
                f32x4 r = o[qt][ht] * inv;
                *(f32x4*)(ob + ht * 16 + quad * 4) = r;
            }
        } else if (sp == 0) {             // split-0 partial lives in out (fp32)
            float* ob = out + grow * HEAD;
            #pragma unroll
            for (int ht = 0; ht < 4; ++ht)
                *(f32x4*)(ob + ht * 16 + quad * 4) = o[qt][ht];
            if (quad == 0) lpart[grow] = lsum[qt];
        } else {                          // splits 1.. -> bf16 opart
            bf16* ob = opart + ((size_t)(sp - 1) * NROWS + grow) * HEAD;
            #pragma unroll
            for (int ht = 0; ht < 4; ++ht) {
                bf16x4 r;
                #pragma unroll
                for (int rr = 0; rr < 4; ++rr) r[rr] = (bf16)o[qt][ht][rr];
                *(bf16x4*)(ob + ht * 16 + quad * 4) = r;
            }
            if (quad == 0) lpart[(size_t)sp * NROWS + grow] = lsum[qt];
        }
    }
}

// ---------------------------------------------------------------------------
// Kernel 3: combine.  Fixed-max partials share one scale -> plain sums.
// ---------------------------------------------------------------------------
__global__ __launch_bounds__(256) void combine(
    const bf16* __restrict__ opart, const float* __restrict__ lpart,
    float* __restrict__ out, int nsplit)
{
    const int gid = blockIdx.x * 256 + threadIdx.x;
    const int row = gid >> 4;
    const int h4  = (gid & 15) * 4;

    float L = 0.f;
    for (int s = 0; s < nsplit; ++s) L += lpart[(size_t)s * NROWS + row];
    f32x4 O = *(const f32x4*)(out + (size_t)row * HEAD + h4);
    for (int s = 1; s < nsplit; ++s) {
        bf16x4 v = *(const bf16x4*)(opart + ((size_t)(s - 1) * NROWS + row) * HEAD + h4);
        O[0] += (float)v[0]; O[1] += (float)v[1];
        O[2] += (float)v[2]; O[3] += (float)v[3];
    }
    f32x4 r = O * (1.f / L);
    *(f32x4*)(out + (size_t)row * HEAD + h4) = r;
}

// ---------------------------------------------------------------------------
extern "C" void kernel_launch(void* const* d_in, const int* in_sizes, int n_in,
                              void* d_out, int out_size, void* d_ws, size_t ws_size,
                              hipStream_t stream) {
    const float* x  = (const float*)d_in[0];
    const float* Wq = (const float*)d_in[1];
    const float* bq = (const float*)d_in[2];
    const float* Wk = (const float*)d_in[3];
    const float* bk = (const float*)d_in[4];
    const float* Wv = (const float*)d_in[5];
    const float* bv = (const float*)d_in[6];
    float* out = (float*)d_out;

    const size_t n_tok = (size_t)NROWS * HEAD;          // 1,048,576
    char* ws = (char*)d_ws;
    bf16* qb = (bf16*)ws;
    bf16* kb = qb + n_tok;
    bf16* vT = kb + n_tok;
    bf16* Wt = vT + n_tok;
    const size_t base = 3 * n_tok * sizeof(bf16) + 192 * CEMB * sizeof(bf16);

    auto need = [&](int S) {
        return base + (size_t)(S - 1) * n_tok * sizeof(bf16)
                    + (size_t)S * NROWS * sizeof(float);
    };
    int S = 1, lg2S = 0;
    if      (ws_size >= need(8)) { S = 8; lg2S = 3; }
    else if (ws_size >= need(4)) { S = 4; lg2S = 2; }
    else if (ws_size >= need(2)) { S = 2; lg2S = 1; }
    bf16*  opart = Wt + 192 * CEMB;
    float* lpart = (float*)(opart + (size_t)(S - 1) * n_tok);

    pack_w<<<dim3(192), dim3(256), 0, stream>>>(Wq, Wk, Wv, Wt);
    qkv<<<dim3(512), dim3(256), 0, stream>>>(x, Wt, bq, bk, bv, qb, kb, vT);
    attn<<<dim3(32 * BATCH * S), dim3(256), 0, stream>>>(
        qb, kb, vT, opart, lpart, out, S, lg2S);
    if (S > 1)
        combine<<<dim3((NROWS * 16) / 256), dim3(256), 0, stream>>>(
            opart, lpart, out, S);
}

// Round 7
// 162.492 us; speedup vs baseline: 1.4106x; 1.1538x over previous
//
#include <hip/hip_runtime.h>
#include <hip/hip_bf16.h>
#include <cmath>

#define BATCH 4
#define TLEN  4096
#define CEMB  1024
#define HEAD  64
#define NROWS (BATCH * TLEN)          // 16384 token rows

typedef __bf16 bf16;
typedef __attribute__((ext_vector_type(8))) __bf16 bf16x8;
typedef __attribute__((ext_vector_type(4))) __bf16 bf16x4;
typedef __attribute__((ext_vector_type(4))) float f32x4;

#define QSCALE 0.1803368801111204f    // (1/sqrt(64)) * log2(e)

static __device__ __forceinline__ f32x4 mfma16(bf16x8 a, bf16x8 b, f32x4 c) {
    return __builtin_amdgcn_mfma_f32_16x16x32_bf16(a, b, c, 0, 0, 0);
}

// async 16B/lane global->LDS DMA.  lds base is WAVE-UNIFORM; lane i's 16 B
// land at base + i*16.  Side-effecting intrinsic -> compiler cannot sink it.
static __device__ __forceinline__ void async_ld16(const void* g, void* l) {
    __builtin_amdgcn_global_load_lds(
        (const __attribute__((address_space(1))) void*)g,
        (__attribute__((address_space(3))) void*)l, 16, 0, 0);
}

// ---------------------------------------------------------------------------
// Kernel 0: pack W -> Wt[n][k] bf16 (n = which*64+h).  QSCALE folded into Wq.
// ---------------------------------------------------------------------------
__global__ __launch_bounds__(256) void pack_w(
    const float* __restrict__ Wq, const float* __restrict__ Wk,
    const float* __restrict__ Wv, bf16* __restrict__ Wt)
{
    const int n = blockIdx.x;                 // 0..191
    const int which = n >> 6, h = n & 63;
    const float* W = which == 0 ? Wq : (which == 1 ? Wk : Wv);
    const float s = which == 0 ? QSCALE : 1.0f;
    for (int k = threadIdx.x; k < CEMB; k += 256)
        Wt[(size_t)n * CEMB + k] = (bf16)(W[(size_t)k * HEAD + h] * s);
}

// ---------------------------------------------------------------------------
// Kernel 1: QKV projection v4.  R6 post-mortem: register-mediated staging is
// always sunk by the scheduler (load issued then immediately vmcnt(0)-waited
// -> full HBM latency exposed per chunk; VALUBusy 2.9%).  Fix: x staged
// fp32 via global_load_lds DMA (unsinkable), double-buffered, k-chunk 64.
// Global source granule XOR-swizzled (c = s ^ (r&7)) so packed-LDS reads are
// bank-balanced.  Wave = 32 rows x 3 n-tiles; Wt B-frags direct from L2-hot
// global.  Grid 512, 2 blocks/CU.
// ---------------------------------------------------------------------------
__global__ __launch_bounds__(256, 2) void qkv(
    const float* __restrict__ x, const bf16* __restrict__ Wt,
    const float* __restrict__ bq, const float* __restrict__ bk,
    const float* __restrict__ bv,
    bf16* __restrict__ qb, bf16* __restrict__ kb, bf16* __restrict__ vT)
{
    __shared__ __align__(16) float Xsh[2][32][64];   // 16 KB, fp32 x chunk

    const int tid  = threadIdx.x;
    const int lane = tid & 63;
    const int wvid = tid >> 6;            // 0..3 -> n-triple
    const int quad = lane >> 4;
    const int col  = lane & 15;
    const int row0 = blockIdx.x * 32;     // grid 512

    const float* xblk = x + (size_t)row0 * CEMB;
    const bf16* wrow[3];
    #pragma unroll
    for (int j = 0; j < 3; ++j)
        wrow[j] = Wt + (size_t)((wvid * 3 + j) * 16 + col) * CEMB + quad * 8;

    // DMA stage: wave issues 2 wave-loads of 4 rows (64 lanes x 16B = 1KB)
    const int sr = lane >> 4;             // row within wave-load 0..3
    const int ss = lane & 15;             // LDS granule slot
    auto stage = [&](int ci, int bufi) {
        #pragma unroll
        for (int j = 0; j < 2; ++j) {
            const int r = wvid * 8 + j * 4 + sr;
            const int c = ss ^ (r & 7);   // global granule (16B = 4 fp32)
            async_ld16(xblk + (size_t)r * CEMB + ci * 64 + c * 4,
                       &Xsh[bufi][wvid * 8 + j * 4][0]);
        }
    };

    f32x4 acc[2][3] = {};                 // [row-tile][n-tile]
    const int c7 = col & 7;

    stage(0, 0);
    int buf = 0;
    for (int ci = 0; ci < 16; ++ci) {
        __syncthreads();                  // implicit vmcnt(0): DMA(ci) visible
        if (ci + 1 < 16) stage(ci + 1, buf ^ 1);   // in flight across compute

        #pragma unroll
        for (int kk = 0; kk < 2; ++kk) {
            const int h = ci * 2 + kk;
            bf16x8 Bv[3];
            #pragma unroll
            for (int j = 0; j < 3; ++j)
                Bv[j] = *(const bf16x8*)(wrow[j] + h * 32);
            #pragma unroll
            for (int rt = 0; rt < 2; ++rt) {
                const int r = rt * 16 + col;
                const int g0 = kk * 8 + quad * 2;
                float4 a0 = *(const float4*)&Xsh[buf][r][(g0 ^ c7) * 4];
                float4 a1 = *(const float4*)&Xsh[buf][r][((g0 + 1) ^ c7) * 4];
                bf16x8 af;
                af[0]=(bf16)a0.x; af[1]=(bf16)a0.y; af[2]=(bf16)a0.z; af[3]=(bf16)a0.w;
                af[4]=(bf16)a1.x; af[5]=(bf16)a1.y; af[6]=(bf16)a1.z; af[7]=(bf16)a1.w;
                #pragma unroll
                for (int j = 0; j < 3; ++j)
                    acc[rt][j] = mfma16(af, Bv[j], acc[rt][j]);
            }
        }
        buf ^= 1;
    }

    const float* bias[3] = {bq, bk, bv};
    #pragma unroll
    for (int j = 0; j < 3; ++j) {
        const int jg = wvid * 3 + j;      // global n-tile 0..11
        const int which = jg >> 2;
        const int h = (jg & 3) * 16 + col;
        float bb = bias[which][h];
        if (which == 0) bb *= QSCALE;
        #pragma unroll
        for (int rt = 0; rt < 2; ++rt) {
            if (which < 2) {
                bf16* dst = which == 0 ? qb : kb;
                #pragma unroll
                for (int r = 0; r < 4; ++r) {
                    const int trow = row0 + rt * 16 + quad * 4 + r;
                    dst[(size_t)trow * HEAD + h] = (bf16)(acc[rt][j][r] + bb);
                }
            } else {                      // v -> vT[b][h][t], 4 contig t
                bf16x4 pv;
                #pragma unroll
                for (int r = 0; r < 4; ++r) pv[r] = (bf16)(acc[rt][j][r] + bb);
                const int trow0 = row0 + rt * 16 + quad * 4;
                const int bb_   = trow0 >> 12;
                const int tt    = trow0 & (TLEN - 1);
                *(bf16x4*)(vT + ((size_t)(bb_ * HEAD + h)) * TLEN + tt) = pv;
            }
        }
    }
}

// ---------------------------------------------------------------------------
// Kernel 2: attention v3.  Same math as R4-R6 (fixed-max softmax, S^T=K.Q^T,
// XCD-locality decode), but K/V staged via global_load_lds DMA (unsinkable,
// double-buffered, one barrier/chunk).  Global granule XOR swizzle matches
// the read-side (quad^c7) indices.  P bounce in dedicated Psh (back buffer
// is DMA-in-flight during compute).
// ---------------------------------------------------------------------------
__global__ __launch_bounds__(256) void attn(
    const bf16* __restrict__ qb, const bf16* __restrict__ kb,
    const bf16* __restrict__ vT,
    bf16* __restrict__ opart, float* __restrict__ lpart,
    float* __restrict__ out, int nsplit, int lg2S)
{
    __shared__ __align__(16) bf16 Ksh[2][64][64];   // 16 KB
    __shared__ __align__(16) bf16 Vsh[2][64][64];   // 16 KB (V^T: [h][s])
    __shared__ __align__(16) bf16 Psh[4][16][64];   // 8 KB per-wave P bounce

    const int tid  = threadIdx.x;
    const int lane = tid & 63;
    const int wvid = tid >> 6;
    const int quad = lane >> 4;
    const int col  = lane & 15;

    int b, sp, qtile;
    {
        const int id = blockIdx.x;
        if (nsplit >= 2) {
            const int cpx = (BATCH << lg2S) >> 3;   // combos per XCD
            const int idx = id >> 3;
            const int combo = (id & 7) * cpx + (idx >> 5);
            qtile = idx & 31;
            b = combo >> lg2S;
            sp = combo & (nsplit - 1);
        } else {
            qtile = id & 31; b = id >> 5; sp = 0;
        }
    }
    const int q0 = qtile * 128 + wvid * 32;
    const size_t rowbase = (size_t)b * TLEN + q0;

    bf16x8 qf[2][2];
    #pragma unroll
    for (int qt = 0; qt < 2; ++qt) {
        const bf16* qp = qb + (rowbase + qt * 16 + col) * HEAD + quad * 8;
        qf[qt][0] = *(const bf16x8*)qp;
        qf[qt][1] = *(const bf16x8*)(qp + 32);
    }
    const bf16* kbB = kb + (size_t)b * TLEN * HEAD;
    const bf16* vTB = vT + (size_t)b * HEAD * TLEN;

    f32x4 o[2][4] = {};
    float lsum[2] = {0.f, 0.f};

    const int slen = TLEN >> lg2S;
    const int sbeg = sp * slen;
    const int nch  = slen / 64;

    // DMA stage: wave stages K rows wvid*16..+15 and V rows (h) same range,
    // 2 wave-loads each of 8 rows (128 B/row).
    const int r8 = lane >> 3;            // 0..7
    const int s8 = lane & 7;
    auto stage = [&](int s0, int bufi) {
        #pragma unroll
        for (int j = 0; j < 2; ++j) {
            const int r = wvid * 16 + j * 8 + r8;
            const int c = s8 ^ (r & 7);  // global granule (16B = 8 bf16)
            async_ld16(kbB + (size_t)(s0 + r) * HEAD + c * 8,
                       &Ksh[bufi][wvid * 16 + j * 8][0]);
            async_ld16(vTB + (size_t)r * TLEN + s0 + c * 8,
                       &Vsh[bufi][wvid * 16 + j * 8][0]);
        }
    };

    stage(sbeg, 0);
    int buf = 0;
    for (int ci = 0; ci < nch; ++ci) {
        __syncthreads();                 // implicit vmcnt(0): DMA(ci) visible
        if (ci + 1 < nch) stage(sbeg + (ci + 1) * 64, buf ^ 1);

        const int c7 = col & 7;
        bf16x8 pb[2][2];
        bf16* Pb = &Psh[wvid][col][0];
        #pragma unroll
        for (int qt = 0; qt < 2; ++qt) {
            f32x4 st[4];
            #pragma unroll
            for (int t = 0; t < 4; ++t) {
                const int r = t * 16 + col;
                bf16x8 k0 = *(const bf16x8*)&Ksh[buf][r][(quad ^ c7) * 8];
                bf16x8 k1 = *(const bf16x8*)&Ksh[buf][r][((4 + quad) ^ c7) * 8];
                f32x4 z = {0.f, 0.f, 0.f, 0.f};
                z = mfma16(k0, qf[qt][0], z);
                z = mfma16(k1, qf[qt][1], z);
                st[t] = z;
            }
            #pragma unroll
            for (int t = 0; t < 4; ++t) {
                float p0 = __builtin_amdgcn_exp2f(st[t][0]);
                float p1 = __builtin_amdgcn_exp2f(st[t][1]);
                float p2 = __builtin_amdgcn_exp2f(st[t][2]);
                float p3 = __builtin_amdgcn_exp2f(st[t][3]);
                lsum[qt] += (p0 + p1) + (p2 + p3);
                bf16x4 pv = {(bf16)p0, (bf16)p1, (bf16)p2, (bf16)p3};
                const int g = ((2 * t + (quad >> 1)) ^ c7) * 8 + (quad & 1) * 4;
                *(bf16x4*)(Pb + g) = pv;
            }
            pb[qt][0] = *(const bf16x8*)(Pb + ((quad ^ c7) * 8));
            pb[qt][1] = *(const bf16x8*)(Pb + (((4 + quad) ^ c7) * 8));
        }
        #pragma unroll
        for (int ht = 0; ht < 4; ++ht) {
            const int r = ht * 16 + col;
            bf16x8 v0 = *(const bf16x8*)&Vsh[buf][r][(quad ^ c7) * 8];
            bf16x8 v1 = *(const bf16x8*)&Vsh[buf][r][((4 + quad) ^ c7) * 8];
            o[0][ht] = mfma16(v0, pb[0][0], o[0][ht]);
            o[0][ht] = mfma16(v1, pb[0][1], o[0][ht]);
            o[1][ht] = mfma16(v0, pb[1][0], o[1][ht]);
            o[1][ht] = mfma16(v1, pb[1][1], o[1][ht]);
        }
        buf ^= 1;
    }

    #pragma unroll
    for (int qt = 0; qt < 2; ++qt) {
        lsum[qt] += __shfl_xor(lsum[qt], 16, 64);
        lsum[qt] += __shfl_xor(lsum[qt], 32, 64);
    }

    #pragma unroll
    for (int qt = 0; qt < 2; ++qt) {
        const size_t grow = rowbase + qt * 16 + col;
        if (nsplit == 1) {
            const float inv = 1.f / lsum[qt];
            float* ob = out + grow * HEAD;
            #pragma unroll
            for (int ht = 0; ht < 4; ++ht) {
                f32x4 r = o[qt][ht] * inv;
                *(f32x4*)(ob + ht * 16 + quad * 4) = r;
            }
        } else if (sp == 0) {             // split-0 partial lives in out (fp32)
            float* ob = out + grow * HEAD;
            #pragma unroll
            for (int ht = 0; ht < 4; ++ht)
                *(f32x4*)(ob + ht * 16 + quad * 4) = o[qt][ht];
            if (quad == 0) lpart[grow] = lsum[qt];
        } else {                          // splits 1.. -> bf16 opart
            bf16* ob = opart + ((size_t)(sp - 1) * NROWS + grow) * HEAD;
            #pragma unroll
            for (int ht = 0; ht < 4; ++ht) {
                bf16x4 r;
                #pragma unroll
                for (int rr = 0; rr < 4; ++rr) r[rr] = (bf16)o[qt][ht][rr];
                *(bf16x4*)(ob + ht * 16 + quad * 4) = r;
            }
            if (quad == 0) lpart[(size_t)sp * NROWS + grow] = lsum[qt];
        }
    }
}

// ---------------------------------------------------------------------------
// Kernel 3: combine.  Fixed-max partials share one scale -> plain sums.
// ---------------------------------------------------------------------------
__global__ __launch_bounds__(256) void combine(
    const bf16* __restrict__ opart, const float* __restrict__ lpart,
    float* __restrict__ out, int nsplit)
{
    const int gid = blockIdx.x * 256 + threadIdx.x;
    const int row = gid >> 4;
    const int h4  = (gid & 15) * 4;

    float L = 0.f;
    for (int s = 0; s < nsplit; ++s) L += lpart[(size_t)s * NROWS + row];
    f32x4 O = *(const f32x4*)(out + (size_t)row * HEAD + h4);
    for (int s = 1; s < nsplit; ++s) {
        bf16x4 v = *(const bf16x4*)(opart + ((size_t)(s - 1) * NROWS + row) * HEAD + h4);
        O[0] += (float)v[0]; O[1] += (float)v[1];
        O[2] += (float)v[2]; O[3] += (float)v[3];
    }
    f32x4 r = O * (1.f / L);
    *(f32x4*)(out + (size_t)row * HEAD + h4) = r;
}

// ---------------------------------------------------------------------------
extern "C" void kernel_launch(void* const* d_in, const int* in_sizes, int n_in,
                              void* d_out, int out_size, void* d_ws, size_t ws_size,
                              hipStream_t stream) {
    const float* x  = (const float*)d_in[0];
    const float* Wq = (const float*)d_in[1];
    const float* bq = (const float*)d_in[2];
    const float* Wk = (const float*)d_in[3];
    const float* bk = (const float*)d_in[4];
    const float* Wv = (const float*)d_in[5];
    const float* bv = (const float*)d_in[6];
    float* out = (float*)d_out;

    const size_t n_tok = (size_t)NROWS * HEAD;          // 1,048,576
    char* ws = (char*)d_ws;
    bf16* qb = (bf16*)ws;
    bf16* kb = qb + n_tok;
    bf16* vT = kb + n_tok;
    bf16* Wt = vT + n_tok;
    const size_t base = 3 * n_tok * sizeof(bf16) + 192 * CEMB * sizeof(bf16);

    auto need = [&](int S) {
        return base + (size_t)(S - 1) * n_tok * sizeof(bf16)
                    + (size_t)S * NROWS * sizeof(float);
    };
    int S = 1, lg2S = 0;
    if      (ws_size >= need(8)) { S = 8; lg2S = 3; }
    else if (ws_size >= need(4)) { S = 4; lg2S = 2; }
    else if (ws_size >= need(2)) { S = 2; lg2S = 1; }
    bf16*  opart = Wt + 192 * CEMB;
    float* lpart = (float*)(opart + (size_t)(S - 1) * n_tok);

    pack_w<<<dim3(192), dim3(256), 0, stream>>>(Wq, Wk, Wv, Wt);
    qkv<<<dim3(512), dim3(256), 0, stream>>>(x, Wt, bq, bk, bv, qb, kb, vT);
    attn<<<dim3(32 * BATCH * S), dim3(256), 0, stream>>>(
        qb, kb, vT, opart, lpart, out, S, lg2S);
    if (S > 1)
        combine<<<dim3((NROWS * 16) / 256), dim3(256), 0, stream>>>(
            opart, lpart, out, S);
}

// Round 8
// 161.322 us; speedup vs baseline: 1.4208x; 1.0073x over previous
//
#include <hip/hip_runtime.h>
#include <hip/hip_bf16.h>
#include <cmath>

#define BATCH 4
#define TLEN  4096
#define CEMB  1024
#define HEAD  64
#define NROWS (BATCH * TLEN)          // 16384 token rows

typedef __bf16 bf16;
typedef __attribute__((ext_vector_type(8))) __bf16 bf16x8;
typedef __attribute__((ext_vector_type(4))) __bf16 bf16x4;
typedef __attribute__((ext_vector_type(4))) float f32x4;

#define QSCALE 0.1803368801111204f    // (1/sqrt(64)) * log2(e)

static __device__ __forceinline__ f32x4 mfma16(bf16x8 a, bf16x8 b, f32x4 c) {
    return __builtin_amdgcn_mfma_f32_16x16x32_bf16(a, b, c, 0, 0, 0);
}

// async 16B/lane global->LDS DMA.  lds base is WAVE-UNIFORM; lane i's 16 B
// land at base + i*16.  Side-effecting intrinsic -> compiler cannot sink it.
static __device__ __forceinline__ void async_ld16(const void* g, void* l) {
    __builtin_amdgcn_global_load_lds(
        (const __attribute__((address_space(1))) void*)g,
        (__attribute__((address_space(3))) void*)l, 16, 0, 0);
}

// ---------------------------------------------------------------------------
// Kernel 0: pack W -> Wt[n][k] bf16 (n = which*64+h).  QSCALE folded into Wq.
// ---------------------------------------------------------------------------
__global__ __launch_bounds__(256) void pack_w(
    const float* __restrict__ Wq, const float* __restrict__ Wk,
    const float* __restrict__ Wv, bf16* __restrict__ Wt)
{
    const int n = blockIdx.x;                 // 0..191
    const int which = n >> 6, h = n & 63;
    const float* W = which == 0 ? Wq : (which == 1 ? Wk : Wv);
    const float s = which == 0 ? QSCALE : 1.0f;
    for (int k = threadIdx.x; k < CEMB; k += 256)
        Wt[(size_t)n * CEMB + k] = (bf16)(W[(size_t)k * HEAD + h] * s);
}

// ---------------------------------------------------------------------------
// Kernel 1: QKV projection v5.  x staged fp32 via global_load_lds DMA,
// double-buffered; k-chunk 128 (two 64-col halves, identical swizzle) -> 8
// barriers instead of 16, 24 mfma/chunk to cover the DMA round-trip.
// Wave = 32 rows x 3 n-tiles; Wt B-frags direct from L2-hot global.
// ---------------------------------------------------------------------------
__global__ __launch_bounds__(256, 2) void qkv(
    const float* __restrict__ x, const bf16* __restrict__ Wt,
    const float* __restrict__ bq, const float* __restrict__ bk,
    const float* __restrict__ bv,
    bf16* __restrict__ qb, bf16* __restrict__ kb, bf16* __restrict__ vT)
{
    __shared__ __align__(16) float Xsh[2][2][32][64];   // 32 KB

    const int tid  = threadIdx.x;
    const int lane = tid & 63;
    const int wvid = tid >> 6;            // 0..3 -> n-triple
    const int quad = lane >> 4;
    const int col  = lane & 15;
    const int row0 = blockIdx.x * 32;     // grid 512

    const float* xblk = x + (size_t)row0 * CEMB;
    const bf16* wrow[3];
    #pragma unroll
    for (int j = 0; j < 3; ++j)
        wrow[j] = Wt + (size_t)((wvid * 3 + j) * 16 + col) * CEMB + quad * 8;

    // DMA stage: per half, wave issues 2 wave-loads of 4 rows (1 KB each)
    const int sr = lane >> 4;             // row within wave-load 0..3
    const int ss = lane & 15;             // LDS granule slot
    auto stage = [&](int ci, int bufi) {
        #pragma unroll
        for (int h2 = 0; h2 < 2; ++h2)
            #pragma unroll
            for (int j = 0; j < 2; ++j) {
                const int r = wvid * 8 + j * 4 + sr;
                const int c = ss ^ (r & 7);   // global granule (16B = 4 fp32)
                async_ld16(xblk + (size_t)r * CEMB + ci * 128 + h2 * 64 + c * 4,
                           &Xsh[bufi][h2][wvid * 8 + j * 4][0]);
            }
    };

    f32x4 acc[2][3] = {};                 // [row-tile][n-tile]
    const int c7 = col & 7;

    stage(0, 0);
    int buf = 0;
    for (int ci = 0; ci < 8; ++ci) {      // 8 chunks of 128 k
        __syncthreads();                  // implicit vmcnt(0): DMA(ci) visible
        if (ci + 1 < 8) stage(ci + 1, buf ^ 1);   // in flight across compute

        #pragma unroll
        for (int kk = 0; kk < 4; ++kk) {  // 4 x 32-k steps
            const int h  = ci * 4 + kk;
            const int hf = kk >> 1;       // which 64-col half
            const int kl = kk & 1;
            bf16x8 Bv[3];
            #pragma unroll
            for (int j = 0; j < 3; ++j)
                Bv[j] = *(const bf16x8*)(wrow[j] + h * 32);
            #pragma unroll
            for (int rt = 0; rt < 2; ++rt) {
                const int r = rt * 16 + col;
                const int g0 = kl * 8 + quad * 2;
                float4 a0 = *(const float4*)&Xsh[buf][hf][r][(g0 ^ c7) * 4];
                float4 a1 = *(const float4*)&Xsh[buf][hf][r][((g0 + 1) ^ c7) * 4];
                bf16x8 af;
                af[0]=(bf16)a0.x; af[1]=(bf16)a0.y; af[2]=(bf16)a0.z; af[3]=(bf16)a0.w;
                af[4]=(bf16)a1.x; af[5]=(bf16)a1.y; af[6]=(bf16)a1.z; af[7]=(bf16)a1.w;
                #pragma unroll
                for (int j = 0; j < 3; ++j)
                    acc[rt][j] = mfma16(af, Bv[j], acc[rt][j]);
            }
        }
        buf ^= 1;
    }

    const float* bias[3] = {bq, bk, bv};
    #pragma unroll
    for (int j = 0; j < 3; ++j) {
        const int jg = wvid * 3 + j;      // global n-tile 0..11
        const int which = jg >> 2;
        const int h = (jg & 3) * 16 + col;
        float bb = bias[which][h];
        if (which == 0) bb *= QSCALE;
        #pragma unroll
        for (int rt = 0; rt < 2; ++rt) {
            if (which < 2) {
                bf16* dst = which == 0 ? qb : kb;
                #pragma unroll
                for (int r = 0; r < 4; ++r) {
                    const int trow = row0 + rt * 16 + quad * 4 + r;
                    dst[(size_t)trow * HEAD + h] = (bf16)(acc[rt][j][r] + bb);
                }
            } else {                      // v -> vT[b][h][t], 4 contig t
                bf16x4 pv;
                #pragma unroll
                for (int r = 0; r < 4; ++r) pv[r] = (bf16)(acc[rt][j][r] + bb);
                const int trow0 = row0 + rt * 16 + quad * 4;
                const int bb_   = trow0 >> 12;
                const int tt    = trow0 & (TLEN - 1);
                *(bf16x4*)(vT + ((size_t)(bb_ * HEAD + h)) * TLEN + tt) = pv;
            }
        }
    }
}

// ---------------------------------------------------------------------------
// Kernel 2: attention v4.  Wave = 64 q-rows (4 q-tiles of 16): K-frags
// hoisted to registers ONCE per chunk (Psh writes otherwise block LDS-load
// CSE across q-tiles) and reused 4x; V-frags reused 4x; 64 mfma per chunk
// per wave vs ~40 DS ops.  K/V staged via global_load_lds DMA, double-
// buffered, one barrier/chunk.  Fixed-max softmax.  XCD-locality decode.
// ---------------------------------------------------------------------------
__global__ __launch_bounds__(256, 2) void attn(
    const bf16* __restrict__ qb, const bf16* __restrict__ kb,
    const bf16* __restrict__ vT,
    bf16* __restrict__ opart, float* __restrict__ lpart,
    float* __restrict__ out, int nsplit, int lg2S)
{
    __shared__ __align__(16) bf16 Ksh[2][64][64];   // 16 KB
    __shared__ __align__(16) bf16 Vsh[2][64][64];   // 16 KB (V^T: [h][s])
    __shared__ __align__(16) bf16 Psh[4][16][64];   // 8 KB per-wave P bounce

    const int tid  = threadIdx.x;
    const int lane = tid & 63;
    const int wvid = tid >> 6;
    const int quad = lane >> 4;
    const int col  = lane & 15;

    // block decode: 16 q-tiles of 256 rows; whole (b,sp) combos per XCD
    int b, sp, qtile;
    {
        const int id = blockIdx.x;
        if (nsplit >= 2) {
            const int cpx = (BATCH << lg2S) >> 3;   // combos per XCD
            const int idx = id >> 3;
            const int combo = (id & 7) * cpx + (idx >> 4);
            qtile = idx & 15;
            b = combo >> lg2S;
            sp = combo & (nsplit - 1);
        } else {
            qtile = id & 15; b = id >> 4; sp = 0;
        }
    }
    const int q0 = qtile * 256 + wvid * 64;
    const size_t rowbase = (size_t)b * TLEN + q0;

    bf16x8 qf[4][2];
    #pragma unroll
    for (int qt = 0; qt < 4; ++qt) {
        const bf16* qp = qb + (rowbase + qt * 16 + col) * HEAD + quad * 8;
        qf[qt][0] = *(const bf16x8*)qp;
        qf[qt][1] = *(const bf16x8*)(qp + 32);
    }
    const bf16* kbB = kb + (size_t)b * TLEN * HEAD;
    const bf16* vTB = vT + (size_t)b * HEAD * TLEN;

    f32x4 o[4][4] = {};                   // [qt][ht]
    float lsum[4] = {0.f, 0.f, 0.f, 0.f};

    const int slen = TLEN >> lg2S;
    const int sbeg = sp * slen;
    const int nch  = slen / 64;

    // DMA stage: wave stages K rows wvid*16..+15 and V rows same range
    const int r8 = lane >> 3;            // 0..7
    const int s8 = lane & 7;
    auto stage = [&](int s0, int bufi) {
        #pragma unroll
        for (int j = 0; j < 2; ++j) {
            const int r = wvid * 16 + j * 8 + r8;
            const int c = s8 ^ (r & 7);  // global granule (16B = 8 bf16)
            async_ld16(kbB + (size_t)(s0 + r) * HEAD + c * 8,
                       &Ksh[bufi][wvid * 16 + j * 8][0]);
            async_ld16(vTB + (size_t)r * TLEN + s0 + c * 8,
                       &Vsh[bufi][wvid * 16 + j * 8][0]);
        }
    };

    stage(sbeg, 0);
    int buf = 0;
    for (int ci = 0; ci < nch; ++ci) {
        __syncthreads();                 // implicit vmcnt(0): DMA(ci) visible
        if (ci + 1 < nch) stage(sbeg + (ci + 1) * 64, buf ^ 1);

        const int c7 = col & 7;
        // K fragments once per chunk, reused across 4 q-tiles
        bf16x8 kf[4][2];
        #pragma unroll
        for (int t = 0; t < 4; ++t) {
            const int r = t * 16 + col;
            kf[t][0] = *(const bf16x8*)&Ksh[buf][r][(quad ^ c7) * 8];
            kf[t][1] = *(const bf16x8*)&Ksh[buf][r][((4 + quad) ^ c7) * 8];
        }
        bf16x8 pb[4][2];
        bf16* Pb = &Psh[wvid][col][0];
        #pragma unroll
        for (int qt = 0; qt < 4; ++qt) {
            f32x4 st[4];
            #pragma unroll
            for (int t = 0; t < 4; ++t) {
                f32x4 z = {0.f, 0.f, 0.f, 0.f};
                z = mfma16(kf[t][0], qf[qt][0], z);
                z = mfma16(kf[t][1], qf[qt][1], z);
                st[t] = z;
            }
            #pragma unroll
            for (int t = 0; t < 4; ++t) {
                float p0 = __builtin_amdgcn_exp2f(st[t][0]);
                float p1 = __builtin_amdgcn_exp2f(st[t][1]);
                float p2 = __builtin_amdgcn_exp2f(st[t][2]);
                float p3 = __builtin_amdgcn_exp2f(st[t][3]);
                lsum[qt] += (p0 + p1) + (p2 + p3);
                bf16x4 pv = {(bf16)p0, (bf16)p1, (bf16)p2, (bf16)p3};
                const int g = ((2 * t + (quad >> 1)) ^ c7) * 8 + (quad & 1) * 4;
                *(bf16x4*)(Pb + g) = pv;
            }
            pb[qt][0] = *(const bf16x8*)(Pb + ((quad ^ c7) * 8));
            pb[qt][1] = *(const bf16x8*)(Pb + (((4 + quad) ^ c7) * 8));
        }
        #pragma unroll
        for (int ht = 0; ht < 4; ++ht) {
            const int r = ht * 16 + col;
            bf16x8 v0 = *(const bf16x8*)&Vsh[buf][r][(quad ^ c7) * 8];
            bf16x8 v1 = *(const bf16x8*)&Vsh[buf][r][((4 + quad) ^ c7) * 8];
            #pragma unroll
            for (int qt = 0; qt < 4; ++qt) {
                o[qt][ht] = mfma16(v0, pb[qt][0], o[qt][ht]);
                o[qt][ht] = mfma16(v1, pb[qt][1], o[qt][ht]);
            }
        }
        buf ^= 1;
    }

    #pragma unroll
    for (int qt = 0; qt < 4; ++qt) {
        lsum[qt] += __shfl_xor(lsum[qt], 16, 64);
        lsum[qt] += __shfl_xor(lsum[qt], 32, 64);
    }

    #pragma unroll
    for (int qt = 0; qt < 4; ++qt) {
        const size_t grow = rowbase + qt * 16 + col;
        if (nsplit == 1) {
            const float inv = 1.f / lsum[qt];
            float* ob = out + grow * HEAD;
            #pragma unroll
            for (int ht = 0; ht < 4; ++ht) {
                f32x4 r = o[qt][ht] * inv;
                *(f32x4*)(ob + ht * 16 + quad * 4) = r;
            }
        } else if (sp == 0) {             // split-0 partial lives in out (fp32)
            float* ob = out + grow * HEAD;
            #pragma unroll
            for (int ht = 0; ht < 4; ++ht)
                *(f32x4*)(ob + ht * 16 + quad * 4) = o[qt][ht];
            if (quad == 0) lpart[grow] = lsum[qt];
        } else {                          // splits 1.. -> bf16 opart
            bf16* ob = opart + ((size_t)(sp - 1) * NROWS + grow) * HEAD;
            #pragma unroll
            for (int ht = 0; ht < 4; ++ht) {
                bf16x4 r;
                #pragma unroll
                for (int rr = 0; rr < 4; ++rr) r[rr] = (bf16)o[qt][ht][rr];
                *(bf16x4*)(ob + ht * 16 + quad * 4) = r;
            }
            if (quad == 0) lpart[(size_t)sp * NROWS + grow] = lsum[qt];
        }
    }
}

// ---------------------------------------------------------------------------
// Kernel 3: combine.  Fixed-max partials share one scale -> plain sums.
// ---------------------------------------------------------------------------
__global__ __launch_bounds__(256) void combine(
    const bf16* __restrict__ opart, const float* __restrict__ lpart,
    float* __restrict__ out, int nsplit)
{
    const int gid = blockIdx.x * 256 + threadIdx.x;
    const int row = gid >> 4;
    const int h4  = (gid & 15) * 4;

    float L = 0.f;
    for (int s = 0; s < nsplit; ++s) L += lpart[(size_t)s * NROWS + row];
    f32x4 O = *(const f32x4*)(out + (size_t)row * HEAD + h4);
    for (int s = 1; s < nsplit; ++s) {
        bf16x4 v = *(const bf16x4*)(opart + ((size_t)(s - 1) * NROWS + row) * HEAD + h4);
        O[0] += (float)v[0]; O[1] += (float)v[1];
        O[2] += (float)v[2]; O[3] += (float)v[3];
    }
    f32x4 r = O * (1.f / L);
    *(f32x4*)(out + (size_t)row * HEAD + h4) = r;
}

// ---------------------------------------------------------------------------
extern "C" void kernel_launch(void* const* d_in, const int* in_sizes, int n_in,
                              void* d_out, int out_size, void* d_ws, size_t ws_size,
                              hipStream_t stream) {
    const float* x  = (const float*)d_in[0];
    const float* Wq = (const float*)d_in[1];
    const float* bq = (const float*)d_in[2];
    const float* Wk = (const float*)d_in[3];
    const float* bk = (const float*)d_in[4];
    const float* Wv = (const float*)d_in[5];
    const float* bv = (const float*)d_in[6];
    float* out = (float*)d_out;

    const size_t n_tok = (size_t)NROWS * HEAD;          // 1,048,576
    char* ws = (char*)d_ws;
    bf16* qb = (bf16*)ws;
    bf16* kb = qb + n_tok;
    bf16* vT = kb + n_tok;
    bf16* Wt = vT + n_tok;
    const size_t base = 3 * n_tok * sizeof(bf16) + 192 * CEMB * sizeof(bf16);

    auto need = [&](int S) {
        return base + (size_t)(S - 1) * n_tok * sizeof(bf16)
                    + (size_t)S * NROWS * sizeof(float);
    };
    int S = 1, lg2S = 0;
    if      (ws_size >= need(8)) { S = 8; lg2S = 3; }
    else if (ws_size >= need(4)) { S = 4; lg2S = 2; }
    else if (ws_size >= need(2)) { S = 2; lg2S = 1; }
    bf16*  opart = Wt + 192 * CEMB;
    float* lpart = (float*)(opart + (size_t)(S - 1) * n_tok);

    pack_w<<<dim3(192), dim3(256), 0, stream>>>(Wq, Wk, Wv, Wt);
    qkv<<<dim3(512), dim3(256), 0, stream>>>(x, Wt, bq, bk, bv, qb, kb, vT);
    attn<<<dim3(16 * BATCH * S), dim3(256), 0, stream>>>(
        qb, kb, vT, opart, lpart, out, S, lg2S);
    if (S > 1)
        combine<<<dim3((NROWS * 16) / 256), dim3(256), 0, stream>>>(
            opart, lpart, out, S);
}